// Round 14
// baseline (333.691 us; speedup 1.0000x reference)
//
#include <hip/hip_runtime.h>
#include <math.h>

typedef __attribute__((ext_vector_type(8))) short short8;
typedef __attribute__((ext_vector_type(4))) short s16x4;
typedef __attribute__((ext_vector_type(4))) float f32x4;
typedef __attribute__((ext_vector_type(4))) unsigned u32x4;

#define R_ROIS 512
#define CCH 512
#define HH 50
#define WW 50
#define PPOOL 7
#define KDIM (CCH * PPOOL * PPOOL) /* 25088 */
#define NH 4096
#define ZSPLIT 8
#define NHEAD 105 /* 84 cls + 21 scores */

// raw barrier: lgkmcnt(0) publishes ds_writes; NO vmcnt drain -> prefetch
// loads stay in flight across the barrier (T4; __syncthreads would drain).
#define BARRIER_NO_VMDRAIN()                              \
  do {                                                    \
    asm volatile("s_waitcnt lgkmcnt(0)" ::: "memory");    \
    __builtin_amdgcn_s_barrier();                         \
  } while (0)

__device__ __forceinline__ short f2bf(float f) {
  unsigned u = __builtin_bit_cast(unsigned, f);
  u += 0x7FFFu + ((u >> 16) & 1u);
  return (short)(u >> 16);
}
__device__ __forceinline__ float bf2f(short s) {
  unsigned u = ((unsigned)(unsigned short)s) << 16;
  return __builtin_bit_cast(float, u);
}
// HW packed fp32->bf16 (RNE): 1 VALU per 2 elements
__device__ __forceinline__ unsigned cvtpk(float lo, float hi) {
  unsigned r;
  asm("v_cvt_pk_bf16_f32 %0, %1, %2" : "=v"(r) : "v"(lo), "v"(hi));
  return r;
}

// ---------------- RoI max pool -> bf16 activation matrix A[512][25088] ---------
// grid (R, 8): blockIdx.y picks a channel eighth. Thread-per-output layout
// (wave spans ~1.3 channels -> small line footprint).
__global__ __launch_bounds__(256) void roi_pool_kernel(
    const float* __restrict__ x, const float* __restrict__ rois,
    const int* __restrict__ ridx, short* __restrict__ A) {
  __shared__ int hs[PPOOL], he[PPOOL], wss[PPOOL], wee[PPOOL];
  __shared__ int sidx;
  const int r = blockIdx.x;
  if (threadIdx.x == 0) {
    // raw rois columns: (ymin, xmin, ymax, xmax); reference permutes to (x,y,x,y)
    float ymin = rois[r * 4 + 0], xmin = rois[r * 4 + 1];
    float ymax = rois[r * 4 + 2], xmax = rois[r * 4 + 3];
    float sw = rintf(xmin * 0.0625f);
    float sh = rintf(ymin * 0.0625f);
    float ew = rintf(xmax * 0.0625f);
    float eh = rintf(ymax * 0.0625f);
    float bw = fmaxf(ew - sw + 1.0f, 1.0f) * (1.0f / 7.0f);
    float bh = fmaxf(eh - sh + 1.0f, 1.0f) * (1.0f / 7.0f);
    for (int p = 0; p < PPOOL; ++p) {
      wss[p] = (int)fminf(fmaxf(floorf(p * bw) + sw, 0.0f), 50.0f);
      wee[p] = (int)fminf(fmaxf(ceilf((p + 1) * bw) + sw, 0.0f), 50.0f);
      hs[p]  = (int)fminf(fmaxf(floorf(p * bh) + sh, 0.0f), 50.0f);
      he[p]  = (int)fminf(fmaxf(ceilf((p + 1) * bh) + sh, 0.0f), 50.0f);
    }
    sidx = ridx[r];
  }
  __syncthreads();
  const float* xb = x + (size_t)sidx * CCH * HH * WW;
  const int obeg = blockIdx.y * (KDIM / 8), oend = obeg + KDIM / 8;
  for (int o = obeg + threadIdx.x; o < oend; o += 256) {
    int c = o / 49;
    int pq = o - c * 49;
    int ph = pq / 7, pw = pq - ph * 7;
    const float* xc = xb + (size_t)c * (HH * WW);
    int h0 = hs[ph], h1 = he[ph], w0 = wss[pw], w1 = wee[pw];
    float mv = -INFINITY;
    for (int h = h0; h < h1; ++h) {
      const float* xr = xc + h * WW;
      for (int w = w0; w < w1; ++w) mv = fmaxf(mv, xr[w]);
    }
    A[(size_t)r * KDIM + o] = f2bf((h1 > h0 && w1 > w0) ? mv : 0.0f);
  }
}

// ---- bf16 MFMA split-K GEMM: BM=256, BN=128, BK=32, 512 thr (4m x 2n waves) --
// grid = 2mb x 32nb x 8z = 512 blocks = 2 blocks/CU: cross-block overlap covers
// the barrier bubbles 1-block/CU lockstep exposed. LDS 48KB/block (96/CU),
// VGPR <=128 (launch_bounds 512,4) so both blocks co-reside. 1-deep register
// prefetch + raw barriers (counted vmcnt; no drain). Chunked XCD swizzle:
// vid>>6 = XCD id -> one z-slice per XCD (A k-slice L2-resident, W read once).
__global__ __launch_bounds__(512, 4) void gemm_splitk_kernel(
    const short* __restrict__ A, const float* __restrict__ B,
    float* __restrict__ part, int M, int N, int K, int Ks, int nblk) {
  __shared__ __align__(16) char As[2][256 * 64];
  __shared__ __align__(16) char Bs[2][128 * 64];
  const int bid = blockIdx.x;
  const int vid = (bid & 7) * (nblk >> 3) + (bid >> 3);
  const int mb = vid & 1;
  const int nb = (vid >> 1) & 31;
  const int zb = vid >> 6;
  const int m0 = mb * 256, n0 = nb * 128;
  const int kbeg = zb * Ks, kend = kbeg + Ks;
  const int t = threadIdx.x;
  const int lane = t & 63, wid = t >> 6;  // 8 waves
  const int wm = wid >> 1, wn = wid & 1;  // 4m x 2n, wave tile 64x64
  const int lr = lane & 15, kc = lane >> 4;
  const int ar = t >> 1, ah = t & 1;      // A staging: row ar, 32B half ah
  const int bn = t & 127, bko = t >> 7;   // B staging: col bn, 8k-octet bko

  const short* aptrA = A + (size_t)(m0 + ar) * K + ah * 16;
  const float* bbase = B + n0 + bn;

  const int awz0 = (ar * 64 + ah * 32) ^ ((ar & 7) << 4);
  const int awz1 = awz0 ^ 16;
  const int bwz = (bn * 64 + bko * 16) ^ ((bn & 7) << 4);
  const int aoff = (wm * 4096 + lr * 64 + kc * 16) ^ ((lr & 7) << 4);
  const int boff = (wn * 4096 + lr * 64 + kc * 16) ^ ((lr & 7) << 4);

  f32x4 acc[4][4] = {};
  short8 a_r0, a_r1;
  float br[8];

  auto LOADT = [&](int k0) {
    a_r0 = *(const short8*)(aptrA + k0);
    a_r1 = *(const short8*)(aptrA + k0 + 8);
    const float* bp = bbase + (size_t)(k0 + bko * 8) * N;
    #pragma unroll
    for (int j = 0; j < 8; ++j) br[j] = bp[(size_t)j * N];
  };
  auto WRITET = [&](int buf) {
    *(short8*)(As[buf] + awz0) = a_r0;
    *(short8*)(As[buf] + awz1) = a_r1;
    u32x4 w;
    w[0] = cvtpk(br[0], br[1]);
    w[1] = cvtpk(br[2], br[3]);
    w[2] = cvtpk(br[4], br[5]);
    w[3] = cvtpk(br[6], br[7]);
    *(u32x4*)(Bs[buf] + bwz) = w;
  };
  auto COMPUTE = [&](int buf) {
    short8 b[4];
    #pragma unroll
    for (int n = 0; n < 4; ++n)
      b[n] = *(const short8*)(Bs[buf] + boff + n * 1024);
    #pragma unroll
    for (int m = 0; m < 4; ++m) {
      short8 a = *(const short8*)(As[buf] + aoff + m * 1024);
      #pragma unroll
      for (int n = 0; n < 4; ++n)
        acc[m][n] = __builtin_amdgcn_mfma_f32_16x16x32_bf16(a, b[n], acc[m][n], 0, 0, 0);
    }
  };

  LOADT(kbeg);
  WRITET(0);
  BARRIER_NO_VMDRAIN();

  int cur = 0;
  for (int k0 = kbeg + 32; k0 <= kend; k0 += 32) {
    bool more = (k0 < kend);
    if (more) LOADT(k0);   // issue next-tile loads (stay in flight past barrier)
    COMPUTE(cur);
    if (more) {
      WRITET(cur ^ 1);     // counted vmcnt wait on this tile's loads only
      BARRIER_NO_VMDRAIN();
      cur ^= 1;
    }
  }

  // ---- write fp32 partial; C/D map: col=lane&15, row=kc*4+j ----
  float* pz = part + (size_t)zb * M * N;
  #pragma unroll
  for (int m = 0; m < 4; ++m) {
    #pragma unroll
    for (int n = 0; n < 4; ++n) {
      int col = n0 + wn * 64 + n * 16 + lr;
      #pragma unroll
      for (int j = 0; j < 4; ++j) {
        int row = m0 + wm * 64 + m * 16 + kc * 4 + j;
        pz[(size_t)row * N + col] = acc[m][n][j];
      }
    }
  }
}

// ---------------- reduce split-K partials + bias + relu -> bf16 ---------------
__global__ __launch_bounds__(256) void reduce_relu_kernel(
    const float* __restrict__ part, const float* __restrict__ bias,
    short* __restrict__ out, int MN, int N) {
  int i = (blockIdx.x * 256 + threadIdx.x) * 4;
  if (i >= MN) return;
  const float4 b = *(const float4*)(bias + (i & (N - 1)));
  float4 s = *(const float4*)(part + i);
  #pragma unroll
  for (int z = 1; z < ZSPLIT; ++z) {
    float4 p = *(const float4*)(part + (size_t)z * MN + i);
    s.x += p.x; s.y += p.y; s.z += p.z; s.w += p.w;
  }
  s16x4 o;
  o.x = f2bf(fmaxf(s.x + b.x, 0.0f));
  o.y = f2bf(fmaxf(s.y + b.y, 0.0f));
  o.z = f2bf(fmaxf(s.z + b.z, 0.0f));
  o.w = f2bf(fmaxf(s.w + b.w, 0.0f));
  *(s16x4*)(out + i) = o;
}

// ------------- pack Wc[4096,84] | Ws[4096,21] -> Wt bf16 [128][4096] ----------
__global__ __launch_bounds__(256) void pack_head_w_kernel(
    const float* __restrict__ Wc, const float* __restrict__ Wsv,
    short* __restrict__ Wt) {
  const int n = blockIdx.x;  // 0..127
  for (int k = threadIdx.x; k < NH; k += 256) {
    float v = 0.0f;
    if (n < 84) v = Wc[(size_t)k * 84 + n];
    else if (n < NHEAD) v = Wsv[(size_t)k * 21 + (n - 84)];
    Wt[(size_t)n * NH + k] = f2bf(v);
  }
}

// ---- head mini-GEMM: fc7[512,4096]bf16 @ Wt[128,4096]bf16 -> part2 fp32 -----
// BM=BN=128, BK=32, 256 thr (4 waves 2x2, wave tile 64x64), grid (4m, 8z).
__global__ __launch_bounds__(256, 2) void gemm_head_kernel(
    const short* __restrict__ A, const short* __restrict__ Bt,
    float* __restrict__ part2) {
  __shared__ __align__(16) char As[2][128 * 64];
  __shared__ __align__(16) char Bs[2][128 * 64];
  const int m0 = blockIdx.x * 128;
  const int zb = blockIdx.y;
  const int kbeg = zb * (NH / ZSPLIT), kend = kbeg + NH / ZSPLIT;
  const int t = threadIdx.x;
  const int lane = t & 63, wid = t >> 6;
  const int wm = wid >> 1, wn = wid & 1;
  const int lr = lane & 15, kc = lane >> 4;
  const int sr = t >> 2, seg = t & 3;

  const short* aptr0 = A + (size_t)(m0 + sr) * NH + seg * 8;
  const short* aptr1 = aptr0 + (size_t)64 * NH;
  const short* bptr0 = Bt + (size_t)sr * NH + seg * 8;
  const short* bptr1 = bptr0 + (size_t)64 * NH;

  const int wz0 = (sr * 64 + seg * 16) ^ ((sr & 7) << 4);
  const int wz1 = wz0 + 4096;
  const int aoff = (wm * 4096 + lr * 64 + kc * 16) ^ ((lr & 7) << 4);
  const int boff = (wn * 4096 + lr * 64 + kc * 16) ^ ((lr & 7) << 4);

  f32x4 acc[4][4] = {};
  short8 a_r0, a_r1, b_r0, b_r1;

  auto LOADT = [&](int k0) {
    a_r0 = *(const short8*)(aptr0 + k0);
    a_r1 = *(const short8*)(aptr1 + k0);
    b_r0 = *(const short8*)(bptr0 + k0);
    b_r1 = *(const short8*)(bptr1 + k0);
  };
  auto WRITET = [&](int buf) {
    *(short8*)(As[buf] + wz0) = a_r0;
    *(short8*)(As[buf] + wz1) = a_r1;
    *(short8*)(Bs[buf] + wz0) = b_r0;
    *(short8*)(Bs[buf] + wz1) = b_r1;
  };
  auto COMPUTE = [&](int buf) {
    short8 a[4], b[4];
    #pragma unroll
    for (int m = 0; m < 4; ++m)
      a[m] = *(const short8*)(As[buf] + aoff + m * 1024);
    #pragma unroll
    for (int n = 0; n < 4; ++n)
      b[n] = *(const short8*)(Bs[buf] + boff + n * 1024);
    #pragma unroll
    for (int m = 0; m < 4; ++m)
      #pragma unroll
      for (int n = 0; n < 4; ++n)
        acc[m][n] = __builtin_amdgcn_mfma_f32_16x16x32_bf16(a[m], b[n], acc[m][n], 0, 0, 0);
  };

  LOADT(kbeg);
  WRITET(0);
  BARRIER_NO_VMDRAIN();

  int cur = 0;
  for (int k0 = kbeg + 32; k0 <= kend; k0 += 32) {
    bool more = (k0 < kend);
    if (more) LOADT(k0);
    COMPUTE(cur);
    if (more) {
      WRITET(cur ^ 1);
      BARRIER_NO_VMDRAIN();
      cur ^= 1;
    }
  }

  float* pz = part2 + (size_t)zb * R_ROIS * 128;
  #pragma unroll
  for (int m = 0; m < 4; ++m) {
    #pragma unroll
    for (int n = 0; n < 4; ++n) {
      int col = wn * 64 + n * 16 + lr;
      #pragma unroll
      for (int j = 0; j < 4; ++j) {
        int row = m0 + wm * 64 + m * 16 + kc * 4 + j;
        pz[(size_t)row * 128 + col] = acc[m][n][j];
      }
    }
  }
}

// --------- reduce head partials + bias, scatter to the two outputs ----------
__global__ __launch_bounds__(128) void reduce_head_kernel(
    const float* __restrict__ part2, const float* __restrict__ bc,
    const float* __restrict__ bs, float* __restrict__ out) {
  const int r = blockIdx.x, c = threadIdx.x;
  if (c >= NHEAD) return;
  float s = 0.0f;
  #pragma unroll
  for (int z = 0; z < ZSPLIT; ++z)
    s += part2[(size_t)z * R_ROIS * 128 + (size_t)r * 128 + c];
  if (c < 84)
    out[(size_t)r * 84 + c] = s + bc[c];
  else
    out[(size_t)R_ROIS * 84 + (size_t)r * 21 + (c - 84)] = s + bs[c - 84];
}

extern "C" void kernel_launch(void* const* d_in, const int* in_sizes, int n_in,
                              void* d_out, int out_size, void* d_ws, size_t ws_size,
                              hipStream_t stream) {
  const float* x    = (const float*)d_in[0];
  const float* rois = (const float*)d_in[1];
  const int*   ridx = (const int*)d_in[2];
  const float* W1   = (const float*)d_in[3];
  const float* b1   = (const float*)d_in[4];
  const float* W2   = (const float*)d_in[5];
  const float* b2   = (const float*)d_in[6];
  const float* Wc   = (const float*)d_in[7];
  const float* bc   = (const float*)d_in[8];
  const float* Wsv  = (const float*)d_in[9];
  const float* bs   = (const float*)d_in[10];

  const int MN = R_ROIS * NH;
  short* A     = (short*)d_ws;                    // [512][25088] bf16 (~25.7 MB)
  short* fc6   = A + (size_t)R_ROIS * KDIM;       // [512][4096]  bf16 (4 MB)
  short* fc7   = fc6 + (size_t)MN;                // [512][4096]  bf16 (4 MB)
  float* part  = (float*)(fc7 + (size_t)MN);      // Z x [512][4096] f32 (67 MB)
  float* part2 = part + (size_t)ZSPLIT * MN;      // Z x [512][128]  f32 (2 MB)
  short* Wt    = (short*)(part2 + (size_t)ZSPLIT * R_ROIS * 128);  // [128][4096] bf16

  roi_pool_kernel<<<dim3(R_ROIS, 8), 256, 0, stream>>>(x, rois, ridx, A);
  pack_head_w_kernel<<<128, 256, 0, stream>>>(Wc, Wsv, Wt);

  // fc6: [512,25088] @ [25088,4096]; grid 2mb x 32nb x 8z = 512 blocks (2/CU)
  gemm_splitk_kernel<<<512, 512, 0, stream>>>(A, W1, part, R_ROIS, NH, KDIM,
                                              KDIM / ZSPLIT, 512);
  reduce_relu_kernel<<<MN / 4 / 256, 256, 0, stream>>>(part, b1, fc6, MN, NH);

  // fc7: [512,4096] @ [4096,4096]
  gemm_splitk_kernel<<<512, 512, 0, stream>>>(fc6, W2, part, R_ROIS, NH, NH,
                                              NH / ZSPLIT, 512);
  reduce_relu_kernel<<<MN / 4 / 256, 256, 0, stream>>>(part, b2, fc7, MN, NH);

  // heads: fc7 @ Wt^T via MFMA mini-GEMM (grid 4m x 8z), then bias+scatter
  gemm_head_kernel<<<dim3(4, ZSPLIT), 256, 0, stream>>>(fc7, Wt, part2);
  reduce_head_kernel<<<R_ROIS, 128, 0, stream>>>(part2, bc, bs, (float*)d_out);
}

// Round 15
// 303.940 us; speedup vs baseline: 1.0979x; 1.0979x over previous
//
#include <hip/hip_runtime.h>
#include <math.h>

typedef __attribute__((ext_vector_type(8))) short short8;
typedef __attribute__((ext_vector_type(4))) short s16x4;
typedef __attribute__((ext_vector_type(4))) float f32x4;
typedef __attribute__((ext_vector_type(4))) unsigned u32x4;

#define R_ROIS 512
#define CCH 512
#define HH 50
#define WW 50
#define PPOOL 7
#define KDIM (CCH * PPOOL * PPOOL) /* 25088 */
#define NH 4096
#define ZSPLIT 8
#define NHEAD 105 /* 84 cls + 21 scores */

// raw barrier: lgkmcnt(0) publishes ds_writes; NO vmcnt drain -> prefetch
// loads stay in flight across the barrier (T4; __syncthreads would drain).
#define BARRIER_NO_VMDRAIN()                              \
  do {                                                    \
    asm volatile("s_waitcnt lgkmcnt(0)" ::: "memory");    \
    __builtin_amdgcn_s_barrier();                         \
  } while (0)

__device__ __forceinline__ short f2bf(float f) {
  unsigned u = __builtin_bit_cast(unsigned, f);
  u += 0x7FFFu + ((u >> 16) & 1u);
  return (short)(u >> 16);
}
__device__ __forceinline__ float bf2f(short s) {
  unsigned u = ((unsigned)(unsigned short)s) << 16;
  return __builtin_bit_cast(float, u);
}
// HW packed fp32->bf16 (RNE): 1 VALU per 2 elements
__device__ __forceinline__ unsigned cvtpk(float lo, float hi) {
  unsigned r;
  asm("v_cvt_pk_bf16_f32 %0, %1, %2" : "=v"(r) : "v"(lo), "v"(hi));
  return r;
}

// ---------------- RoI max pool -> bf16 activation matrix A[512][25088] ---------
// grid (R, 8). Input spec: roi wh in [32,128]px -> <=10 cells -> bw,bh < 1.43
// -> per-output span <= 3 in both axes (proof: ceil((p+1)b)-floor(pb) <=
// ceil(b)+1 = 3). Static 3x3 unrolled clamped+masked loads: 9 independent
// loads, one waitcnt, zero divergence (replaces the serial data-dependent
// nest whose wave cost was max-span iterations of load->fmax chains).
__global__ __launch_bounds__(256) void roi_pool_kernel(
    const float* __restrict__ x, const float* __restrict__ rois,
    const int* __restrict__ ridx, short* __restrict__ A) {
  __shared__ int hs[PPOOL], he[PPOOL], wss[PPOOL], wee[PPOOL];
  __shared__ int sidx;
  const int r = blockIdx.x;
  if (threadIdx.x == 0) {
    // raw rois columns: (ymin, xmin, ymax, xmax); reference permutes to (x,y,x,y)
    float ymin = rois[r * 4 + 0], xmin = rois[r * 4 + 1];
    float ymax = rois[r * 4 + 2], xmax = rois[r * 4 + 3];
    float sw = rintf(xmin * 0.0625f);
    float sh = rintf(ymin * 0.0625f);
    float ew = rintf(xmax * 0.0625f);
    float eh = rintf(ymax * 0.0625f);
    float bw = fmaxf(ew - sw + 1.0f, 1.0f) * (1.0f / 7.0f);
    float bh = fmaxf(eh - sh + 1.0f, 1.0f) * (1.0f / 7.0f);
    for (int p = 0; p < PPOOL; ++p) {
      wss[p] = (int)fminf(fmaxf(floorf(p * bw) + sw, 0.0f), 50.0f);
      wee[p] = (int)fminf(fmaxf(ceilf((p + 1) * bw) + sw, 0.0f), 50.0f);
      hs[p]  = (int)fminf(fmaxf(floorf(p * bh) + sh, 0.0f), 50.0f);
      he[p]  = (int)fminf(fmaxf(ceilf((p + 1) * bh) + sh, 0.0f), 50.0f);
    }
    sidx = ridx[r];
  }
  __syncthreads();
  const float* xb = x + (size_t)sidx * CCH * HH * WW;
  const int obeg = blockIdx.y * (KDIM / 8), oend = obeg + KDIM / 8;
  for (int o = obeg + threadIdx.x; o < oend; o += 256) {
    int c = o / 49;
    int pq = o - c * 49;
    int ph = pq / 7, pw = pq - ph * 7;
    const float* xc = xb + (size_t)c * (HH * WW);
    int h0 = hs[ph], h1 = he[ph], w0 = wss[pw], w1 = wee[pw];
    float mv = -INFINITY;
    #pragma unroll
    for (int i = 0; i < 3; ++i) {
      int h = h0 + i;
      const float* xr = xc + (h < HH - 1 ? h : HH - 1) * WW;
      #pragma unroll
      for (int j = 0; j < 3; ++j) {
        int w = w0 + j;
        float f = xr[w < WW - 1 ? w : WW - 1];
        if (h < h1 && w < w1) mv = fmaxf(mv, f);
      }
    }
    A[(size_t)r * KDIM + o] = f2bf((h1 > h0 && w1 > w0) ? mv : 0.0f);
  }
}

// ---- bf16 MFMA split-K GEMM: BM=BN=256, BK=32, 512 thr, wave tile 128x64 ----
// grid = 2m x 16n x 8z = 256 blocks (1/CU). 2-deep register prefetch with TWO
// named reg sets + raw-barrier steps (lgkmcnt only): tile i+2's loads stay in
// flight across the barrier (counted vmcnt at their ds_write), giving ~2
// compute phases (~2000cy) to cover the ~900cy HBM latency. Chunked XCD
// swizzle: one z-slice per XCD (A k-slice L2-resident, W HBM-streamed once).
// [R14 lesson: 256x128 2-blocks/CU is WORSE (-40us) - intensity beats overlap.]
__global__ __launch_bounds__(512, 2) void gemm_splitk_kernel(
    const short* __restrict__ A, const float* __restrict__ B,
    float* __restrict__ part, int M, int N, int K, int Ks, int nblk) {
  __shared__ __align__(16) char As[2][256 * 64];
  __shared__ __align__(16) char Bs[2][256 * 64];
  const int bid = blockIdx.x;
  const int vid = (bid & 7) * (nblk >> 3) + (bid >> 3);
  const int mb = vid & 1;
  const int nb = (vid >> 1) & 15;
  const int zb = vid >> 5;
  const int m0 = mb * 256, n0 = nb * 256;
  const int kbeg = zb * Ks;
  const int S = Ks >> 5;  // K-steps; even for all our shapes
  const int t = threadIdx.x;
  const int lane = t & 63, wid = t >> 6;  // 8 waves
  const int wm = wid >> 2, wn = wid & 3;  // 2m x 4n, wave tile 128x64
  const int lr = lane & 15, kc = lane >> 4;
  const int ar = t >> 1, ah = t & 1;      // A staging: row ar, 32B half ah
  const int bn = t & 255, bko = t >> 8;   // B staging: col bn, 16k-group bko

  const short* aptrA = A + (size_t)(m0 + ar) * K + ah * 16;
  const float* bbase = B + n0 + bn;

  const int awz0 = (ar * 64 + ah * 32) ^ ((ar & 7) << 4);
  const int awz1 = awz0 ^ 16;
  const int bwz0 = (bn * 64 + bko * 32) ^ ((bn & 7) << 4);
  const int bwz1 = bwz0 ^ 16;
  const int aoff = (wm * 8192 + lr * 64 + kc * 16) ^ ((lr & 7) << 4);
  const int boff = (wn * 4096 + lr * 64 + kc * 16) ^ ((lr & 7) << 4);

  f32x4 acc[8][4] = {};
  // two named prefetch reg sets (static indexing -> stays in VGPRs)
  short8 aA0, aA1, aB0, aB1;
  float bA[16], bB[16];

  auto LOADT = [&](int k0, short8& r0, short8& r1, float* br) {
    r0 = *(const short8*)(aptrA + k0);
    r1 = *(const short8*)(aptrA + k0 + 8);
    const float* bp = bbase + (size_t)(k0 + bko * 16) * N;
    #pragma unroll
    for (int j = 0; j < 16; ++j) br[j] = bp[(size_t)j * N];
  };
  auto WRITET = [&](int buf, const short8& r0, const short8& r1, const float* br) {
    *(short8*)(As[buf] + awz0) = r0;
    *(short8*)(As[buf] + awz1) = r1;
    u32x4 w0, w1;
    w0[0] = cvtpk(br[0], br[1]);   w0[1] = cvtpk(br[2], br[3]);
    w0[2] = cvtpk(br[4], br[5]);   w0[3] = cvtpk(br[6], br[7]);
    w1[0] = cvtpk(br[8], br[9]);   w1[1] = cvtpk(br[10], br[11]);
    w1[2] = cvtpk(br[12], br[13]); w1[3] = cvtpk(br[14], br[15]);
    *(u32x4*)(Bs[buf] + bwz0) = w0;
    *(u32x4*)(Bs[buf] + bwz1) = w1;
  };
  auto COMPUTE = [&](int buf) {
    short8 b[4];
    #pragma unroll
    for (int n = 0; n < 4; ++n)
      b[n] = *(const short8*)(Bs[buf] + boff + n * 1024);
    #pragma unroll
    for (int m = 0; m < 8; ++m) {
      short8 a = *(const short8*)(As[buf] + aoff + m * 1024);
      #pragma unroll
      for (int n = 0; n < 4; ++n)
        acc[m][n] = __builtin_amdgcn_mfma_f32_16x16x32_bf16(a, b[n], acc[m][n], 0, 0, 0);
    }
  };

  // prologue: tile0 -> LDS buf0; tile1 -> reg set B
  LOADT(kbeg, aA0, aA1, bA);
  WRITET(0, aA0, aA1, bA);
  LOADT(kbeg + 32, aB0, aB1, bB);
  BARRIER_NO_VMDRAIN();

  int cur = 0;
  for (int i = 0; i < S; i += 2) {
    // even step: compute tile i; set B holds tile i+1; prefetch i+2 -> set A
    if (i + 2 < S) LOADT(kbeg + (i + 2) * 32, aA0, aA1, bA);
    COMPUTE(cur);
    WRITET(cur ^ 1, aB0, aB1, bB);  // counted vmcnt (set-A loads stay in flight)
    BARRIER_NO_VMDRAIN();
    cur ^= 1;
    // odd step: compute tile i+1; set A holds tile i+2; prefetch i+3 -> set B
    if (i + 3 < S) LOADT(kbeg + (i + 3) * 32, aB0, aB1, bB);
    COMPUTE(cur);
    if (i + 2 < S) {
      WRITET(cur ^ 1, aA0, aA1, bA);
      BARRIER_NO_VMDRAIN();
      cur ^= 1;
    }
  }

  // ---- write fp32 partial; C/D map: col=lane&15, row=kc*4+j ----
  float* pz = part + (size_t)zb * M * N;
  #pragma unroll
  for (int m = 0; m < 8; ++m) {
    #pragma unroll
    for (int n = 0; n < 4; ++n) {
      int col = n0 + wn * 64 + n * 16 + lr;
      #pragma unroll
      for (int j = 0; j < 4; ++j) {
        int row = m0 + wm * 128 + m * 16 + kc * 4 + j;
        pz[(size_t)row * N + col] = acc[m][n][j];
      }
    }
  }
}

// ---------------- reduce split-K partials + bias + relu -> bf16 ---------------
__global__ __launch_bounds__(256) void reduce_relu_kernel(
    const float* __restrict__ part, const float* __restrict__ bias,
    short* __restrict__ out, int MN, int N) {
  int i = (blockIdx.x * 256 + threadIdx.x) * 4;
  if (i >= MN) return;
  const float4 b = *(const float4*)(bias + (i & (N - 1)));
  float4 s = *(const float4*)(part + i);
  #pragma unroll
  for (int z = 1; z < ZSPLIT; ++z) {
    float4 p = *(const float4*)(part + (size_t)z * MN + i);
    s.x += p.x; s.y += p.y; s.z += p.z; s.w += p.w;
  }
  s16x4 o;
  o.x = f2bf(fmaxf(s.x + b.x, 0.0f));
  o.y = f2bf(fmaxf(s.y + b.y, 0.0f));
  o.z = f2bf(fmaxf(s.z + b.z, 0.0f));
  o.w = f2bf(fmaxf(s.w + b.w, 0.0f));
  *(s16x4*)(out + i) = o;
}

// ------------- pack Wc[4096,84] | Ws[4096,21] -> Wt bf16 [128][4096] ----------
__global__ __launch_bounds__(256) void pack_head_w_kernel(
    const float* __restrict__ Wc, const float* __restrict__ Wsv,
    short* __restrict__ Wt) {
  const int n = blockIdx.x;  // 0..127
  for (int k = threadIdx.x; k < NH; k += 256) {
    float v = 0.0f;
    if (n < 84) v = Wc[(size_t)k * 84 + n];
    else if (n < NHEAD) v = Wsv[(size_t)k * 21 + (n - 84)];
    Wt[(size_t)n * NH + k] = f2bf(v);
  }
}

// ---- head mini-GEMM: fc7[512,4096]bf16 @ Wt[128,4096]bf16 -> part2 fp32 -----
// BM=BN=128, BK=32, 256 thr (4 waves 2x2, wave tile 64x64), grid (4m, 8z).
__global__ __launch_bounds__(256, 2) void gemm_head_kernel(
    const short* __restrict__ A, const short* __restrict__ Bt,
    float* __restrict__ part2) {
  __shared__ __align__(16) char As[2][128 * 64];
  __shared__ __align__(16) char Bs[2][128 * 64];
  const int m0 = blockIdx.x * 128;
  const int zb = blockIdx.y;
  const int kbeg = zb * (NH / ZSPLIT), kend = kbeg + NH / ZSPLIT;
  const int t = threadIdx.x;
  const int lane = t & 63, wid = t >> 6;
  const int wm = wid >> 1, wn = wid & 1;
  const int lr = lane & 15, kc = lane >> 4;
  const int sr = t >> 2, seg = t & 3;

  const short* aptr0 = A + (size_t)(m0 + sr) * NH + seg * 8;
  const short* aptr1 = aptr0 + (size_t)64 * NH;
  const short* bptr0 = Bt + (size_t)sr * NH + seg * 8;
  const short* bptr1 = bptr0 + (size_t)64 * NH;

  const int wz0 = (sr * 64 + seg * 16) ^ ((sr & 7) << 4);
  const int wz1 = wz0 + 4096;
  const int aoff = (wm * 4096 + lr * 64 + kc * 16) ^ ((lr & 7) << 4);
  const int boff = (wn * 4096 + lr * 64 + kc * 16) ^ ((lr & 7) << 4);

  f32x4 acc[4][4] = {};
  short8 a_r0, a_r1, b_r0, b_r1;

  auto LOADT = [&](int k0) {
    a_r0 = *(const short8*)(aptr0 + k0);
    a_r1 = *(const short8*)(aptr1 + k0);
    b_r0 = *(const short8*)(bptr0 + k0);
    b_r1 = *(const short8*)(bptr1 + k0);
  };
  auto WRITET = [&](int buf) {
    *(short8*)(As[buf] + wz0) = a_r0;
    *(short8*)(As[buf] + wz1) = a_r1;
    *(short8*)(Bs[buf] + wz0) = b_r0;
    *(short8*)(Bs[buf] + wz1) = b_r1;
  };
  auto COMPUTE = [&](int buf) {
    short8 a[4], b[4];
    #pragma unroll
    for (int m = 0; m < 4; ++m)
      a[m] = *(const short8*)(As[buf] + aoff + m * 1024);
    #pragma unroll
    for (int n = 0; n < 4; ++n)
      b[n] = *(const short8*)(Bs[buf] + boff + n * 1024);
    #pragma unroll
    for (int m = 0; m < 4; ++m)
      #pragma unroll
      for (int n = 0; n < 4; ++n)
        acc[m][n] = __builtin_amdgcn_mfma_f32_16x16x32_bf16(a[m], b[n], acc[m][n], 0, 0, 0);
  };

  LOADT(kbeg);
  WRITET(0);
  BARRIER_NO_VMDRAIN();

  int cur = 0;
  for (int k0 = kbeg + 32; k0 <= kend; k0 += 32) {
    bool more = (k0 < kend);
    if (more) LOADT(k0);
    COMPUTE(cur);
    if (more) {
      WRITET(cur ^ 1);
      BARRIER_NO_VMDRAIN();
      cur ^= 1;
    }
  }

  float* pz = part2 + (size_t)zb * R_ROIS * 128;
  #pragma unroll
  for (int m = 0; m < 4; ++m) {
    #pragma unroll
    for (int n = 0; n < 4; ++n) {
      int col = wn * 64 + n * 16 + lr;
      #pragma unroll
      for (int j = 0; j < 4; ++j) {
        int row = m0 + wm * 64 + m * 16 + kc * 4 + j;
        pz[(size_t)row * 128 + col] = acc[m][n][j];
      }
    }
  }
}

// --------- reduce head partials + bias, scatter to the two outputs ----------
__global__ __launch_bounds__(128) void reduce_head_kernel(
    const float* __restrict__ part2, const float* __restrict__ bc,
    const float* __restrict__ bs, float* __restrict__ out) {
  const int r = blockIdx.x, c = threadIdx.x;
  if (c >= NHEAD) return;
  float s = 0.0f;
  #pragma unroll
  for (int z = 0; z < ZSPLIT; ++z)
    s += part2[(size_t)z * R_ROIS * 128 + (size_t)r * 128 + c];
  if (c < 84)
    out[(size_t)r * 84 + c] = s + bc[c];
  else
    out[(size_t)R_ROIS * 84 + (size_t)r * 21 + (c - 84)] = s + bs[c - 84];
}

extern "C" void kernel_launch(void* const* d_in, const int* in_sizes, int n_in,
                              void* d_out, int out_size, void* d_ws, size_t ws_size,
                              hipStream_t stream) {
  const float* x    = (const float*)d_in[0];
  const float* rois = (const float*)d_in[1];
  const int*   ridx = (const int*)d_in[2];
  const float* W1   = (const float*)d_in[3];
  const float* b1   = (const float*)d_in[4];
  const float* W2   = (const float*)d_in[5];
  const float* b2   = (const float*)d_in[6];
  const float* Wc   = (const float*)d_in[7];
  const float* bc   = (const float*)d_in[8];
  const float* Wsv  = (const float*)d_in[9];
  const float* bs   = (const float*)d_in[10];

  const int MN = R_ROIS * NH;
  short* A     = (short*)d_ws;                    // [512][25088] bf16 (~25.7 MB)
  short* fc6   = A + (size_t)R_ROIS * KDIM;       // [512][4096]  bf16 (4 MB)
  short* fc7   = fc6 + (size_t)MN;                // [512][4096]  bf16 (4 MB)
  float* part  = (float*)(fc7 + (size_t)MN);      // Z x [512][4096] f32 (67 MB)
  float* part2 = part + (size_t)ZSPLIT * MN;      // Z x [512][128]  f32 (2 MB)
  short* Wt    = (short*)(part2 + (size_t)ZSPLIT * R_ROIS * 128);  // [128][4096] bf16

  roi_pool_kernel<<<dim3(R_ROIS, 8), 256, 0, stream>>>(x, rois, ridx, A);
  pack_head_w_kernel<<<128, 256, 0, stream>>>(Wc, Wsv, Wt);

  // fc6: [512,25088] @ [25088,4096]; grid 2m x 16n x 8z = 256 blocks (1/CU)
  gemm_splitk_kernel<<<256, 512, 0, stream>>>(A, W1, part, R_ROIS, NH, KDIM,
                                              KDIM / ZSPLIT, 256);
  reduce_relu_kernel<<<MN / 4 / 256, 256, 0, stream>>>(part, b1, fc6, MN, NH);

  // fc7: [512,4096] @ [4096,4096]
  gemm_splitk_kernel<<<256, 512, 0, stream>>>(fc6, W2, part, R_ROIS, NH, NH,
                                              NH / ZSPLIT, 256);
  reduce_relu_kernel<<<MN / 4 / 256, 256, 0, stream>>>(part, b2, fc7, MN, NH);

  // heads: fc7 @ Wt^T via MFMA mini-GEMM (grid 4m x 8z), then bias+scatter
  gemm_head_kernel<<<dim3(4, ZSPLIT), 256, 0, stream>>>(fc7, Wt, part2);
  reduce_head_kernel<<<R_ROIS, 128, 0, stream>>>(part2, bc, bs, (float*)d_out);
}

// Round 16
// 299.862 us; speedup vs baseline: 1.1128x; 1.0136x over previous
//
#include <hip/hip_runtime.h>
#include <math.h>

typedef __attribute__((ext_vector_type(8))) short short8;
typedef __attribute__((ext_vector_type(4))) short s16x4;
typedef __attribute__((ext_vector_type(4))) float f32x4;
typedef __attribute__((ext_vector_type(4))) unsigned u32x4;

#define R_ROIS 512
#define CCH 512
#define HH 50
#define WW 50
#define PPOOL 7
#define KDIM (CCH * PPOOL * PPOOL) /* 25088 */
#define NH 4096
#define ZSPLIT 8   /* fc6 */
#define ZF7 2      /* fc7 */
#define NHEAD 105  /* 84 cls + 21 scores */

// raw barrier: lgkmcnt(0) publishes ds_writes; NO vmcnt drain -> prefetch
// loads stay in flight across the barrier (T4; __syncthreads would drain).
#define BARRIER_NO_VMDRAIN()                              \
  do {                                                    \
    asm volatile("s_waitcnt lgkmcnt(0)" ::: "memory");    \
    __builtin_amdgcn_s_barrier();                         \
  } while (0)

__device__ __forceinline__ short f2bf(float f) {
  unsigned u = __builtin_bit_cast(unsigned, f);
  u += 0x7FFFu + ((u >> 16) & 1u);
  return (short)(u >> 16);
}
__device__ __forceinline__ float bf2f(short s) {
  unsigned u = ((unsigned)(unsigned short)s) << 16;
  return __builtin_bit_cast(float, u);
}
// HW packed fp32->bf16 (RNE): 1 VALU per 2 elements
__device__ __forceinline__ unsigned cvtpk(float lo, float hi) {
  unsigned r;
  asm("v_cvt_pk_bf16_f32 %0, %1, %2" : "=v"(r) : "v"(lo), "v"(hi));
  return r;
}

// ---------------- RoI max pool -> bf16 activation matrix A[512][25088] ---------
// grid (R, 8). Dynamic bounds nest (R15 lesson: static 3x3 always-9-loads was
// +10us vs this ~5.3-load average; masked lanes still pay VMEM issue).
__global__ __launch_bounds__(256) void roi_pool_kernel(
    const float* __restrict__ x, const float* __restrict__ rois,
    const int* __restrict__ ridx, short* __restrict__ A) {
  __shared__ int hs[PPOOL], he[PPOOL], wss[PPOOL], wee[PPOOL];
  __shared__ int sidx;
  const int r = blockIdx.x;
  if (threadIdx.x == 0) {
    // raw rois columns: (ymin, xmin, ymax, xmax); reference permutes to (x,y,x,y)
    float ymin = rois[r * 4 + 0], xmin = rois[r * 4 + 1];
    float ymax = rois[r * 4 + 2], xmax = rois[r * 4 + 3];
    float sw = rintf(xmin * 0.0625f);
    float sh = rintf(ymin * 0.0625f);
    float ew = rintf(xmax * 0.0625f);
    float eh = rintf(ymax * 0.0625f);
    float bw = fmaxf(ew - sw + 1.0f, 1.0f) * (1.0f / 7.0f);
    float bh = fmaxf(eh - sh + 1.0f, 1.0f) * (1.0f / 7.0f);
    for (int p = 0; p < PPOOL; ++p) {
      wss[p] = (int)fminf(fmaxf(floorf(p * bw) + sw, 0.0f), 50.0f);
      wee[p] = (int)fminf(fmaxf(ceilf((p + 1) * bw) + sw, 0.0f), 50.0f);
      hs[p]  = (int)fminf(fmaxf(floorf(p * bh) + sh, 0.0f), 50.0f);
      he[p]  = (int)fminf(fmaxf(ceilf((p + 1) * bh) + sh, 0.0f), 50.0f);
    }
    sidx = ridx[r];
  }
  __syncthreads();
  const float* xb = x + (size_t)sidx * CCH * HH * WW;
  const int obeg = blockIdx.y * (KDIM / 8), oend = obeg + KDIM / 8;
  for (int o = obeg + threadIdx.x; o < oend; o += 256) {
    int c = o / 49;
    int pq = o - c * 49;
    int ph = pq / 7, pw = pq - ph * 7;
    const float* xc = xb + (size_t)c * (HH * WW);
    int h0 = hs[ph], h1 = he[ph], w0 = wss[pw], w1 = wee[pw];
    float mv = -INFINITY;
    for (int h = h0; h < h1; ++h) {
      const float* xr = xc + h * WW;
      for (int w = w0; w < w1; ++w) mv = fmaxf(mv, xr[w]);
    }
    A[(size_t)r * KDIM + o] = f2bf((h1 > h0 && w1 > w0) ? mv : 0.0f);
  }
}

// ---- fc6 GEMM: BM=BN=256, BK=32, 512 thr, wave tile 128x64, Z=8 -------------
// grid = 2m x 16n x 8z = 256 blocks (1/CU). 2-deep register prefetch with TWO
// named reg sets + raw-barrier steps: tile i+2's loads stay in flight across
// the barrier (counted vmcnt at their ds_write). Chunked XCD swizzle: one
// z-slice per XCD (A k-slice L2-resident, W HBM-streamed once).
// [R14 lesson: 256x128 2-blocks/CU is WORSE - intensity beats overlap.]
__global__ __launch_bounds__(512, 2) void gemm_splitk_kernel(
    const short* __restrict__ A, const float* __restrict__ B,
    float* __restrict__ part, int M, int N, int K, int Ks, int nblk) {
  __shared__ __align__(16) char As[2][256 * 64];
  __shared__ __align__(16) char Bs[2][256 * 64];
  const int bid = blockIdx.x;
  const int vid = (bid & 7) * (nblk >> 3) + (bid >> 3);
  const int mb = vid & 1;
  const int nb = (vid >> 1) & 15;
  const int zb = vid >> 5;
  const int m0 = mb * 256, n0 = nb * 256;
  const int kbeg = zb * Ks;
  const int S = Ks >> 5;
  const int t = threadIdx.x;
  const int lane = t & 63, wid = t >> 6;  // 8 waves
  const int wm = wid >> 2, wn = wid & 3;  // 2m x 4n, wave tile 128x64
  const int lr = lane & 15, kc = lane >> 4;
  const int ar = t >> 1, ah = t & 1;      // A staging: row ar, 32B half ah
  const int bn = t & 255, bko = t >> 8;   // B staging: col bn, 16k-group bko

  const short* aptrA = A + (size_t)(m0 + ar) * K + ah * 16;
  const float* bbase = B + n0 + bn;

  const int awz0 = (ar * 64 + ah * 32) ^ ((ar & 7) << 4);
  const int awz1 = awz0 ^ 16;
  const int bwz0 = (bn * 64 + bko * 32) ^ ((bn & 7) << 4);
  const int bwz1 = bwz0 ^ 16;
  const int aoff = (wm * 8192 + lr * 64 + kc * 16) ^ ((lr & 7) << 4);
  const int boff = (wn * 4096 + lr * 64 + kc * 16) ^ ((lr & 7) << 4);

  f32x4 acc[8][4] = {};
  short8 aA0, aA1, aB0, aB1;
  float bA[16], bB[16];

  auto LOADT = [&](int k0, short8& r0, short8& r1, float* br) {
    r0 = *(const short8*)(aptrA + k0);
    r1 = *(const short8*)(aptrA + k0 + 8);
    const float* bp = bbase + (size_t)(k0 + bko * 16) * N;
    #pragma unroll
    for (int j = 0; j < 16; ++j) br[j] = bp[(size_t)j * N];
  };
  auto WRITET = [&](int buf, const short8& r0, const short8& r1, const float* br) {
    *(short8*)(As[buf] + awz0) = r0;
    *(short8*)(As[buf] + awz1) = r1;
    u32x4 w0, w1;
    w0[0] = cvtpk(br[0], br[1]);   w0[1] = cvtpk(br[2], br[3]);
    w0[2] = cvtpk(br[4], br[5]);   w0[3] = cvtpk(br[6], br[7]);
    w1[0] = cvtpk(br[8], br[9]);   w1[1] = cvtpk(br[10], br[11]);
    w1[2] = cvtpk(br[12], br[13]); w1[3] = cvtpk(br[14], br[15]);
    *(u32x4*)(Bs[buf] + bwz0) = w0;
    *(u32x4*)(Bs[buf] + bwz1) = w1;
  };
  auto COMPUTE = [&](int buf) {
    short8 b[4];
    #pragma unroll
    for (int n = 0; n < 4; ++n)
      b[n] = *(const short8*)(Bs[buf] + boff + n * 1024);
    #pragma unroll
    for (int m = 0; m < 8; ++m) {
      short8 a = *(const short8*)(As[buf] + aoff + m * 1024);
      #pragma unroll
      for (int n = 0; n < 4; ++n)
        acc[m][n] = __builtin_amdgcn_mfma_f32_16x16x32_bf16(a, b[n], acc[m][n], 0, 0, 0);
    }
  };

  LOADT(kbeg, aA0, aA1, bA);
  WRITET(0, aA0, aA1, bA);
  LOADT(kbeg + 32, aB0, aB1, bB);
  BARRIER_NO_VMDRAIN();

  int cur = 0;
  for (int i = 0; i < S; i += 2) {
    if (i + 2 < S) LOADT(kbeg + (i + 2) * 32, aA0, aA1, bA);
    COMPUTE(cur);
    WRITET(cur ^ 1, aB0, aB1, bB);
    BARRIER_NO_VMDRAIN();
    cur ^= 1;
    if (i + 3 < S) LOADT(kbeg + (i + 3) * 32, aB0, aB1, bB);
    COMPUTE(cur);
    if (i + 2 < S) {
      WRITET(cur ^ 1, aA0, aA1, bA);
      BARRIER_NO_VMDRAIN();
      cur ^= 1;
    }
  }

  float* pz = part + (size_t)zb * M * N;
  #pragma unroll
  for (int m = 0; m < 8; ++m) {
    #pragma unroll
    for (int n = 0; n < 4; ++n) {
      int col = n0 + wn * 64 + n * 16 + lr;
      #pragma unroll
      for (int j = 0; j < 4; ++j) {
        int row = m0 + wm * 128 + m * 16 + kc * 4 + j;
        pz[(size_t)row * N + col] = acc[m][n][j];
      }
    }
  }
}

// ---- fc7 GEMM: BM=BN=128, BK=32, 256 thr (2x2 waves, 64x64), Z=2 ------------
// grid = 4m x 32n x 2z = 256 blocks (1/CU). Cuts split-K partial traffic from
// 134MB (Z=8) to 34MB. Same 2-deep prefetch + raw barriers (steps ~375cy <
// 900cy latency -> 2-deep required). XCD chunk: 4 XCDs/z, A k-slice (2MB) L2.
__global__ __launch_bounds__(256, 2) void gemm128_splitk_kernel(
    const short* __restrict__ A, const float* __restrict__ B,
    float* __restrict__ part, int M, int N, int K, int Ks, int nblk) {
  __shared__ __align__(16) char As[2][128 * 64];
  __shared__ __align__(16) char Bs[2][128 * 64];
  const int bid = blockIdx.x;
  const int vid = (bid & 7) * (nblk >> 3) + (bid >> 3);
  const int mb = vid & 3;
  const int nb = (vid >> 2) & 31;
  const int zb = vid >> 7;
  const int m0 = mb * 128, n0 = nb * 128;
  const int kbeg = zb * Ks;
  const int S = Ks >> 5;  // 64 for fc7: even
  const int t = threadIdx.x;
  const int lane = t & 63, wid = t >> 6;  // 4 waves
  const int wm = wid >> 1, wn = wid & 1;  // 2m x 2n, wave tile 64x64
  const int lr = lane & 15, kc = lane >> 4;
  const int ar = t >> 1, ah = t & 1;      // A staging: row ar, 32B half ah
  const int bn = t & 127, bkh = t >> 7;   // B staging: col bn, 16k-half bkh

  const short* aptrA = A + (size_t)(m0 + ar) * K + ah * 16;
  const float* bbase = B + n0 + bn;

  const int awz0 = (ar * 64 + ah * 32) ^ ((ar & 7) << 4);
  const int awz1 = awz0 ^ 16;
  const int bwz0 = (bn * 64 + bkh * 32) ^ ((bn & 7) << 4);
  const int bwz1 = bwz0 ^ 16;
  const int aoff = (wm * 4096 + lr * 64 + kc * 16) ^ ((lr & 7) << 4);
  const int boff = (wn * 4096 + lr * 64 + kc * 16) ^ ((lr & 7) << 4);

  f32x4 acc[4][4] = {};
  short8 aA0, aA1, aB0, aB1;
  float bA[16], bB[16];

  auto LOADT = [&](int k0, short8& r0, short8& r1, float* br) {
    r0 = *(const short8*)(aptrA + k0);
    r1 = *(const short8*)(aptrA + k0 + 8);
    const float* bp = bbase + (size_t)(k0 + bkh * 16) * N;
    #pragma unroll
    for (int j = 0; j < 16; ++j) br[j] = bp[(size_t)j * N];
  };
  auto WRITET = [&](int buf, const short8& r0, const short8& r1, const float* br) {
    *(short8*)(As[buf] + awz0) = r0;
    *(short8*)(As[buf] + awz1) = r1;
    u32x4 w0, w1;
    w0[0] = cvtpk(br[0], br[1]);   w0[1] = cvtpk(br[2], br[3]);
    w0[2] = cvtpk(br[4], br[5]);   w0[3] = cvtpk(br[6], br[7]);
    w1[0] = cvtpk(br[8], br[9]);   w1[1] = cvtpk(br[10], br[11]);
    w1[2] = cvtpk(br[12], br[13]); w1[3] = cvtpk(br[14], br[15]);
    *(u32x4*)(Bs[buf] + bwz0) = w0;
    *(u32x4*)(Bs[buf] + bwz1) = w1;
  };
  auto COMPUTE = [&](int buf) {
    short8 a[4], b[4];
    #pragma unroll
    for (int m = 0; m < 4; ++m)
      a[m] = *(const short8*)(As[buf] + aoff + m * 1024);
    #pragma unroll
    for (int n = 0; n < 4; ++n)
      b[n] = *(const short8*)(Bs[buf] + boff + n * 1024);
    #pragma unroll
    for (int m = 0; m < 4; ++m)
      #pragma unroll
      for (int n = 0; n < 4; ++n)
        acc[m][n] = __builtin_amdgcn_mfma_f32_16x16x32_bf16(a[m], b[n], acc[m][n], 0, 0, 0);
  };

  LOADT(kbeg, aA0, aA1, bA);
  WRITET(0, aA0, aA1, bA);
  LOADT(kbeg + 32, aB0, aB1, bB);
  BARRIER_NO_VMDRAIN();

  int cur = 0;
  for (int i = 0; i < S; i += 2) {
    if (i + 2 < S) LOADT(kbeg + (i + 2) * 32, aA0, aA1, bA);
    COMPUTE(cur);
    WRITET(cur ^ 1, aB0, aB1, bB);
    BARRIER_NO_VMDRAIN();
    cur ^= 1;
    if (i + 3 < S) LOADT(kbeg + (i + 3) * 32, aB0, aB1, bB);
    COMPUTE(cur);
    if (i + 2 < S) {
      WRITET(cur ^ 1, aA0, aA1, bA);
      BARRIER_NO_VMDRAIN();
      cur ^= 1;
    }
  }

  float* pz = part + (size_t)zb * M * N;
  #pragma unroll
  for (int m = 0; m < 4; ++m) {
    #pragma unroll
    for (int n = 0; n < 4; ++n) {
      int col = n0 + wn * 64 + n * 16 + lr;
      #pragma unroll
      for (int j = 0; j < 4; ++j) {
        int row = m0 + wm * 64 + m * 16 + kc * 4 + j;
        pz[(size_t)row * N + col] = acc[m][n][j];
      }
    }
  }
}

// ---------------- reduce split-K partials + bias + relu -> bf16 ---------------
__global__ __launch_bounds__(256) void reduce_relu_kernel(
    const float* __restrict__ part, const float* __restrict__ bias,
    short* __restrict__ out, int MN, int N, int Z) {
  int i = (blockIdx.x * 256 + threadIdx.x) * 4;
  if (i >= MN) return;
  const float4 b = *(const float4*)(bias + (i & (N - 1)));
  float4 s = *(const float4*)(part + i);
  for (int z = 1; z < Z; ++z) {
    float4 p = *(const float4*)(part + (size_t)z * MN + i);
    s.x += p.x; s.y += p.y; s.z += p.z; s.w += p.w;
  }
  s16x4 o;
  o.x = f2bf(fmaxf(s.x + b.x, 0.0f));
  o.y = f2bf(fmaxf(s.y + b.y, 0.0f));
  o.z = f2bf(fmaxf(s.z + b.z, 0.0f));
  o.w = f2bf(fmaxf(s.w + b.w, 0.0f));
  *(s16x4*)(out + i) = o;
}

// ------------- pack Wc[4096,84] | Ws[4096,21] -> Wt bf16 [128][4096] ----------
__global__ __launch_bounds__(256) void pack_head_w_kernel(
    const float* __restrict__ Wc, const float* __restrict__ Wsv,
    short* __restrict__ Wt) {
  const int n = blockIdx.x;  // 0..127
  for (int k = threadIdx.x; k < NH; k += 256) {
    float v = 0.0f;
    if (n < 84) v = Wc[(size_t)k * 84 + n];
    else if (n < NHEAD) v = Wsv[(size_t)k * 21 + (n - 84)];
    Wt[(size_t)n * NH + k] = f2bf(v);
  }
}

// ---- head mini-GEMM: fc7[512,4096]bf16 @ Wt[128,4096]bf16 -> part2 fp32 -----
// BM=BN=128, BK=32, 256 thr (4 waves 2x2, wave tile 64x64), grid (4m, 8z).
__global__ __launch_bounds__(256, 2) void gemm_head_kernel(
    const short* __restrict__ A, const short* __restrict__ Bt,
    float* __restrict__ part2) {
  __shared__ __align__(16) char As[2][128 * 64];
  __shared__ __align__(16) char Bs[2][128 * 64];
  const int m0 = blockIdx.x * 128;
  const int zb = blockIdx.y;
  const int kbeg = zb * (NH / ZSPLIT), kend = kbeg + NH / ZSPLIT;
  const int t = threadIdx.x;
  const int lane = t & 63, wid = t >> 6;
  const int wm = wid >> 1, wn = wid & 1;
  const int lr = lane & 15, kc = lane >> 4;
  const int sr = t >> 2, seg = t & 3;

  const short* aptr0 = A + (size_t)(m0 + sr) * NH + seg * 8;
  const short* aptr1 = aptr0 + (size_t)64 * NH;
  const short* bptr0 = Bt + (size_t)sr * NH + seg * 8;
  const short* bptr1 = bptr0 + (size_t)64 * NH;

  const int wz0 = (sr * 64 + seg * 16) ^ ((sr & 7) << 4);
  const int wz1 = wz0 + 4096;
  const int aoff = (wm * 4096 + lr * 64 + kc * 16) ^ ((lr & 7) << 4);
  const int boff = (wn * 4096 + lr * 64 + kc * 16) ^ ((lr & 7) << 4);

  f32x4 acc[4][4] = {};
  short8 a_r0, a_r1, b_r0, b_r1;

  auto LOADT = [&](int k0) {
    a_r0 = *(const short8*)(aptr0 + k0);
    a_r1 = *(const short8*)(aptr1 + k0);
    b_r0 = *(const short8*)(bptr0 + k0);
    b_r1 = *(const short8*)(bptr1 + k0);
  };
  auto WRITET = [&](int buf) {
    *(short8*)(As[buf] + wz0) = a_r0;
    *(short8*)(As[buf] + wz1) = a_r1;
    *(short8*)(Bs[buf] + wz0) = b_r0;
    *(short8*)(Bs[buf] + wz1) = b_r1;
  };
  auto COMPUTE = [&](int buf) {
    short8 a[4], b[4];
    #pragma unroll
    for (int m = 0; m < 4; ++m)
      a[m] = *(const short8*)(As[buf] + aoff + m * 1024);
    #pragma unroll
    for (int n = 0; n < 4; ++n)
      b[n] = *(const short8*)(Bs[buf] + boff + n * 1024);
    #pragma unroll
    for (int m = 0; m < 4; ++m)
      #pragma unroll
      for (int n = 0; n < 4; ++n)
        acc[m][n] = __builtin_amdgcn_mfma_f32_16x16x32_bf16(a[m], b[n], acc[m][n], 0, 0, 0);
  };

  LOADT(kbeg);
  WRITET(0);
  BARRIER_NO_VMDRAIN();

  int cur = 0;
  for (int k0 = kbeg + 32; k0 <= kend; k0 += 32) {
    bool more = (k0 < kend);
    if (more) LOADT(k0);
    COMPUTE(cur);
    if (more) {
      WRITET(cur ^ 1);
      BARRIER_NO_VMDRAIN();
      cur ^= 1;
    }
  }

  float* pz = part2 + (size_t)zb * R_ROIS * 128;
  #pragma unroll
  for (int m = 0; m < 4; ++m) {
    #pragma unroll
    for (int n = 0; n < 4; ++n) {
      int col = wn * 64 + n * 16 + lr;
      #pragma unroll
      for (int j = 0; j < 4; ++j) {
        int row = m0 + wm * 64 + m * 16 + kc * 4 + j;
        pz[(size_t)row * 128 + col] = acc[m][n][j];
      }
    }
  }
}

// --------- reduce head partials + bias, scatter to the two outputs ----------
__global__ __launch_bounds__(128) void reduce_head_kernel(
    const float* __restrict__ part2, const float* __restrict__ bc,
    const float* __restrict__ bs, float* __restrict__ out) {
  const int r = blockIdx.x, c = threadIdx.x;
  if (c >= NHEAD) return;
  float s = 0.0f;
  #pragma unroll
  for (int z = 0; z < ZSPLIT; ++z)
    s += part2[(size_t)z * R_ROIS * 128 + (size_t)r * 128 + c];
  if (c < 84)
    out[(size_t)r * 84 + c] = s + bc[c];
  else
    out[(size_t)R_ROIS * 84 + (size_t)r * 21 + (c - 84)] = s + bs[c - 84];
}

extern "C" void kernel_launch(void* const* d_in, const int* in_sizes, int n_in,
                              void* d_out, int out_size, void* d_ws, size_t ws_size,
                              hipStream_t stream) {
  const float* x    = (const float*)d_in[0];
  const float* rois = (const float*)d_in[1];
  const int*   ridx = (const int*)d_in[2];
  const float* W1   = (const float*)d_in[3];
  const float* b1   = (const float*)d_in[4];
  const float* W2   = (const float*)d_in[5];
  const float* b2   = (const float*)d_in[6];
  const float* Wc   = (const float*)d_in[7];
  const float* bc   = (const float*)d_in[8];
  const float* Wsv  = (const float*)d_in[9];
  const float* bs   = (const float*)d_in[10];

  const int MN = R_ROIS * NH;
  short* A     = (short*)d_ws;                    // [512][25088] bf16 (~25.7 MB)
  short* fc6   = A + (size_t)R_ROIS * KDIM;       // [512][4096]  bf16 (4 MB)
  short* fc7   = fc6 + (size_t)MN;                // [512][4096]  bf16 (4 MB)
  float* part  = (float*)(fc7 + (size_t)MN);      // 8 x [512][4096] f32 (67 MB)
  float* part2 = part + (size_t)ZSPLIT * MN;      // 8 x [512][128]  f32 (2 MB)
  short* Wt    = (short*)(part2 + (size_t)ZSPLIT * R_ROIS * 128);  // [128][4096] bf16

  roi_pool_kernel<<<dim3(R_ROIS, 8), 256, 0, stream>>>(x, rois, ridx, A);
  pack_head_w_kernel<<<128, 256, 0, stream>>>(Wc, Wsv, Wt);

  // fc6: [512,25088] @ [25088,4096]; 256 blocks (1/CU), Z=8
  gemm_splitk_kernel<<<256, 512, 0, stream>>>(A, W1, part, R_ROIS, NH, KDIM,
                                              KDIM / ZSPLIT, 256);
  reduce_relu_kernel<<<MN / 4 / 256, 256, 0, stream>>>(part, b1, fc6, MN, NH, ZSPLIT);

  // fc7: [512,4096] @ [4096,4096]; 128^2 tiles, 256 blocks (1/CU), Z=2
  gemm128_splitk_kernel<<<256, 256, 0, stream>>>(fc6, W2, part, R_ROIS, NH, NH,
                                                 NH / ZF7, 256);
  reduce_relu_kernel<<<MN / 4 / 256, 256, 0, stream>>>(part, b2, fc7, MN, NH, ZF7);

  // heads: fc7 @ Wt^T via MFMA mini-GEMM (grid 4m x 8z), then bias+scatter
  gemm_head_kernel<<<dim3(4, ZSPLIT), 256, 0, stream>>>(fc7, Wt, part2);
  reduce_head_kernel<<<R_ROIS, 128, 0, stream>>>(part2, bc, bs, (float*)d_out);
}

// Round 17
// 290.339 us; speedup vs baseline: 1.1493x; 1.0328x over previous
//
#include <hip/hip_runtime.h>
#include <math.h>

typedef __attribute__((ext_vector_type(8))) short short8;
typedef __attribute__((ext_vector_type(4))) short s16x4;
typedef __attribute__((ext_vector_type(4))) float f32x4;
typedef __attribute__((ext_vector_type(4))) unsigned u32x4;

#define R_ROIS 512
#define CCH 512
#define HH 50
#define WW 50
#define PPOOL 7
#define KDIM (CCH * PPOOL * PPOOL) /* 25088 */
#define NH 4096
#define ZSPLIT 8
#define NHEAD 105 /* 84 cls + 21 scores */
#define POOL_SLICES 16

// raw barrier: lgkmcnt(0) publishes ds_writes; NO vmcnt drain -> prefetch
// loads stay in flight across the barrier (T4; __syncthreads would drain).
#define BARRIER_NO_VMDRAIN()                              \
  do {                                                    \
    asm volatile("s_waitcnt lgkmcnt(0)" ::: "memory");    \
    __builtin_amdgcn_s_barrier();                         \
  } while (0)

__device__ __forceinline__ short f2bf(float f) {
  unsigned u = __builtin_bit_cast(unsigned, f);
  u += 0x7FFFu + ((u >> 16) & 1u);
  return (short)(u >> 16);
}
__device__ __forceinline__ float bf2f(short s) {
  unsigned u = ((unsigned)(unsigned short)s) << 16;
  return __builtin_bit_cast(float, u);
}
// HW packed fp32->bf16 (RNE): 1 VALU per 2 elements
__device__ __forceinline__ unsigned cvtpk(float lo, float hi) {
  unsigned r;
  asm("v_cvt_pk_bf16_f32 %0, %1, %2" : "=v"(r) : "v"(lo), "v"(hi));
  return r;
}

// ---------------- RoI max pool -> bf16 activation matrix A[512][25088] ---------
// grid (R, 16): more TLP for the latency-bound gather (~6 outputs/thread).
// Dynamic bounds nest (R15 lesson: static 3x3 always-9-loads was +10us).
// Thread-per-output layout (R11 lesson: channel-per-thread is 64x worse).
__global__ __launch_bounds__(256) void roi_pool_kernel(
    const float* __restrict__ x, const float* __restrict__ rois,
    const int* __restrict__ ridx, short* __restrict__ A) {
  __shared__ int hs[PPOOL], he[PPOOL], wss[PPOOL], wee[PPOOL];
  __shared__ int sidx;
  const int r = blockIdx.x;
  if (threadIdx.x == 0) {
    // raw rois columns: (ymin, xmin, ymax, xmax); reference permutes to (x,y,x,y)
    float ymin = rois[r * 4 + 0], xmin = rois[r * 4 + 1];
    float ymax = rois[r * 4 + 2], xmax = rois[r * 4 + 3];
    float sw = rintf(xmin * 0.0625f);
    float sh = rintf(ymin * 0.0625f);
    float ew = rintf(xmax * 0.0625f);
    float eh = rintf(ymax * 0.0625f);
    float bw = fmaxf(ew - sw + 1.0f, 1.0f) * (1.0f / 7.0f);
    float bh = fmaxf(eh - sh + 1.0f, 1.0f) * (1.0f / 7.0f);
    for (int p = 0; p < PPOOL; ++p) {
      wss[p] = (int)fminf(fmaxf(floorf(p * bw) + sw, 0.0f), 50.0f);
      wee[p] = (int)fminf(fmaxf(ceilf((p + 1) * bw) + sw, 0.0f), 50.0f);
      hs[p]  = (int)fminf(fmaxf(floorf(p * bh) + sh, 0.0f), 50.0f);
      he[p]  = (int)fminf(fmaxf(ceilf((p + 1) * bh) + sh, 0.0f), 50.0f);
    }
    sidx = ridx[r];
  }
  __syncthreads();
  const float* xb = x + (size_t)sidx * CCH * HH * WW;
  const int obeg = blockIdx.y * (KDIM / POOL_SLICES);
  const int oend = obeg + KDIM / POOL_SLICES;
  for (int o = obeg + threadIdx.x; o < oend; o += 256) {
    int c = o / 49;
    int pq = o - c * 49;
    int ph = pq / 7, pw = pq - ph * 7;
    const float* xc = xb + (size_t)c * (HH * WW);
    int h0 = hs[ph], h1 = he[ph], w0 = wss[pw], w1 = wee[pw];
    float mv = -INFINITY;
    for (int h = h0; h < h1; ++h) {
      const float* xr = xc + h * WW;
      for (int w = w0; w < w1; ++w) mv = fmaxf(mv, xr[w]);
    }
    A[(size_t)r * KDIM + o] = f2bf((h1 > h0 && w1 > w0) ? mv : 0.0f);
  }
}

// ---- bf16 MFMA split-K GEMM: BM=BN=256, BK=32, 512 thr, wave tile 128x64 ----
// grid = 2m x 16n x 8z = 256 blocks (1/CU). 2-deep register prefetch with TWO
// named reg sets + raw-barrier steps: tile i+2's loads stay in flight across
// the barrier (counted vmcnt at their ds_write). Chunked XCD swizzle: one
// z-slice per XCD (A k-slice L2-resident, W HBM-streamed once).
// [R14 lesson: 256x128 2-blocks/CU is WORSE; R16 lesson: 128^2 Z=2 fc7 is
// neutral-negative (4 waves/CU latency exposure) - this kernel serves BOTH.]
__global__ __launch_bounds__(512, 2) void gemm_splitk_kernel(
    const short* __restrict__ A, const float* __restrict__ B,
    float* __restrict__ part, int M, int N, int K, int Ks, int nblk) {
  __shared__ __align__(16) char As[2][256 * 64];
  __shared__ __align__(16) char Bs[2][256 * 64];
  const int bid = blockIdx.x;
  const int vid = (bid & 7) * (nblk >> 3) + (bid >> 3);
  const int mb = vid & 1;
  const int nb = (vid >> 1) & 15;
  const int zb = vid >> 5;
  const int m0 = mb * 256, n0 = nb * 256;
  const int kbeg = zb * Ks;
  const int S = Ks >> 5;
  const int t = threadIdx.x;
  const int lane = t & 63, wid = t >> 6;  // 8 waves
  const int wm = wid >> 2, wn = wid & 3;  // 2m x 4n, wave tile 128x64
  const int lr = lane & 15, kc = lane >> 4;
  const int ar = t >> 1, ah = t & 1;      // A staging: row ar, 32B half ah
  const int bn = t & 255, bko = t >> 8;   // B staging: col bn, 16k-group bko

  const short* aptrA = A + (size_t)(m0 + ar) * K + ah * 16;
  const float* bbase = B + n0 + bn;

  const int awz0 = (ar * 64 + ah * 32) ^ ((ar & 7) << 4);
  const int awz1 = awz0 ^ 16;
  const int bwz0 = (bn * 64 + bko * 32) ^ ((bn & 7) << 4);
  const int bwz1 = bwz0 ^ 16;
  const int aoff = (wm * 8192 + lr * 64 + kc * 16) ^ ((lr & 7) << 4);
  const int boff = (wn * 4096 + lr * 64 + kc * 16) ^ ((lr & 7) << 4);

  f32x4 acc[8][4] = {};
  short8 aA0, aA1, aB0, aB1;
  float bA[16], bB[16];

  auto LOADT = [&](int k0, short8& r0, short8& r1, float* br) {
    r0 = *(const short8*)(aptrA + k0);
    r1 = *(const short8*)(aptrA + k0 + 8);
    const float* bp = bbase + (size_t)(k0 + bko * 16) * N;
    #pragma unroll
    for (int j = 0; j < 16; ++j) br[j] = bp[(size_t)j * N];
  };
  auto WRITET = [&](int buf, const short8& r0, const short8& r1, const float* br) {
    *(short8*)(As[buf] + awz0) = r0;
    *(short8*)(As[buf] + awz1) = r1;
    u32x4 w0, w1;
    w0[0] = cvtpk(br[0], br[1]);   w0[1] = cvtpk(br[2], br[3]);
    w0[2] = cvtpk(br[4], br[5]);   w0[3] = cvtpk(br[6], br[7]);
    w1[0] = cvtpk(br[8], br[9]);   w1[1] = cvtpk(br[10], br[11]);
    w1[2] = cvtpk(br[12], br[13]); w1[3] = cvtpk(br[14], br[15]);
    *(u32x4*)(Bs[buf] + bwz0) = w0;
    *(u32x4*)(Bs[buf] + bwz1) = w1;
  };
  auto COMPUTE = [&](int buf) {
    short8 b[4];
    #pragma unroll
    for (int n = 0; n < 4; ++n)
      b[n] = *(const short8*)(Bs[buf] + boff + n * 1024);
    #pragma unroll
    for (int m = 0; m < 8; ++m) {
      short8 a = *(const short8*)(As[buf] + aoff + m * 1024);
      #pragma unroll
      for (int n = 0; n < 4; ++n)
        acc[m][n] = __builtin_amdgcn_mfma_f32_16x16x32_bf16(a, b[n], acc[m][n], 0, 0, 0);
    }
  };

  LOADT(kbeg, aA0, aA1, bA);
  WRITET(0, aA0, aA1, bA);
  LOADT(kbeg + 32, aB0, aB1, bB);
  BARRIER_NO_VMDRAIN();

  int cur = 0;
  for (int i = 0; i < S; i += 2) {
    if (i + 2 < S) LOADT(kbeg + (i + 2) * 32, aA0, aA1, bA);
    COMPUTE(cur);
    WRITET(cur ^ 1, aB0, aB1, bB);
    BARRIER_NO_VMDRAIN();
    cur ^= 1;
    if (i + 3 < S) LOADT(kbeg + (i + 3) * 32, aB0, aB1, bB);
    COMPUTE(cur);
    if (i + 2 < S) {
      WRITET(cur ^ 1, aA0, aA1, bA);
      BARRIER_NO_VMDRAIN();
      cur ^= 1;
    }
  }

  float* pz = part + (size_t)zb * M * N;
  #pragma unroll
  for (int m = 0; m < 8; ++m) {
    #pragma unroll
    for (int n = 0; n < 4; ++n) {
      int col = n0 + wn * 64 + n * 16 + lr;
      #pragma unroll
      for (int j = 0; j < 4; ++j) {
        int row = m0 + wm * 128 + m * 16 + kc * 4 + j;
        pz[(size_t)row * N + col] = acc[m][n][j];
      }
    }
  }
}

// ---------------- reduce split-K partials + bias + relu -> bf16 ---------------
__global__ __launch_bounds__(256) void reduce_relu_kernel(
    const float* __restrict__ part, const float* __restrict__ bias,
    short* __restrict__ out, int MN, int N) {
  int i = (blockIdx.x * 256 + threadIdx.x) * 4;
  if (i >= MN) return;
  const float4 b = *(const float4*)(bias + (i & (N - 1)));
  float4 s = *(const float4*)(part + i);
  #pragma unroll
  for (int z = 1; z < ZSPLIT; ++z) {
    float4 p = *(const float4*)(part + (size_t)z * MN + i);
    s.x += p.x; s.y += p.y; s.z += p.z; s.w += p.w;
  }
  s16x4 o;
  o.x = f2bf(fmaxf(s.x + b.x, 0.0f));
  o.y = f2bf(fmaxf(s.y + b.y, 0.0f));
  o.z = f2bf(fmaxf(s.z + b.z, 0.0f));
  o.w = f2bf(fmaxf(s.w + b.w, 0.0f));
  *(s16x4*)(out + i) = o;
}

// ------------- pack Wc[4096,84] | Ws[4096,21] -> Wt bf16 [128][4096] ----------
__global__ __launch_bounds__(256) void pack_head_w_kernel(
    const float* __restrict__ Wc, const float* __restrict__ Wsv,
    short* __restrict__ Wt) {
  const int n = blockIdx.x;  // 0..127
  for (int k = threadIdx.x; k < NH; k += 256) {
    float v = 0.0f;
    if (n < 84) v = Wc[(size_t)k * 84 + n];
    else if (n < NHEAD) v = Wsv[(size_t)k * 21 + (n - 84)];
    Wt[(size_t)n * NH + k] = f2bf(v);
  }
}

// ---- head mini-GEMM: fc7[512,4096]bf16 @ Wt[128,4096]bf16 -> part2 fp32 -----
// BM=BN=128, BK=32, 256 thr (4 waves 2x2, wave tile 64x64), grid (4m, 8z).
__global__ __launch_bounds__(256, 2) void gemm_head_kernel(
    const short* __restrict__ A, const short* __restrict__ Bt,
    float* __restrict__ part2) {
  __shared__ __align__(16) char As[2][128 * 64];
  __shared__ __align__(16) char Bs[2][128 * 64];
  const int m0 = blockIdx.x * 128;
  const int zb = blockIdx.y;
  const int kbeg = zb * (NH / ZSPLIT), kend = kbeg + NH / ZSPLIT;
  const int t = threadIdx.x;
  const int lane = t & 63, wid = t >> 6;
  const int wm = wid >> 1, wn = wid & 1;
  const int lr = lane & 15, kc = lane >> 4;
  const int sr = t >> 2, seg = t & 3;

  const short* aptr0 = A + (size_t)(m0 + sr) * NH + seg * 8;
  const short* aptr1 = aptr0 + (size_t)64 * NH;
  const short* bptr0 = Bt + (size_t)sr * NH + seg * 8;
  const short* bptr1 = bptr0 + (size_t)64 * NH;

  const int wz0 = (sr * 64 + seg * 16) ^ ((sr & 7) << 4);
  const int wz1 = wz0 + 4096;
  const int aoff = (wm * 4096 + lr * 64 + kc * 16) ^ ((lr & 7) << 4);
  const int boff = (wn * 4096 + lr * 64 + kc * 16) ^ ((lr & 7) << 4);

  f32x4 acc[4][4] = {};
  short8 a_r0, a_r1, b_r0, b_r1;

  auto LOADT = [&](int k0) {
    a_r0 = *(const short8*)(aptr0 + k0);
    a_r1 = *(const short8*)(aptr1 + k0);
    b_r0 = *(const short8*)(bptr0 + k0);
    b_r1 = *(const short8*)(bptr1 + k0);
  };
  auto WRITET = [&](int buf) {
    *(short8*)(As[buf] + wz0) = a_r0;
    *(short8*)(As[buf] + wz1) = a_r1;
    *(short8*)(Bs[buf] + wz0) = b_r0;
    *(short8*)(Bs[buf] + wz1) = b_r1;
  };
  auto COMPUTE = [&](int buf) {
    short8 a[4], b[4];
    #pragma unroll
    for (int m = 0; m < 4; ++m)
      a[m] = *(const short8*)(As[buf] + aoff + m * 1024);
    #pragma unroll
    for (int n = 0; n < 4; ++n)
      b[n] = *(const short8*)(Bs[buf] + boff + n * 1024);
    #pragma unroll
    for (int m = 0; m < 4; ++m)
      #pragma unroll
      for (int n = 0; n < 4; ++n)
        acc[m][n] = __builtin_amdgcn_mfma_f32_16x16x32_bf16(a[m], b[n], acc[m][n], 0, 0, 0);
  };

  LOADT(kbeg);
  WRITET(0);
  BARRIER_NO_VMDRAIN();

  int cur = 0;
  for (int k0 = kbeg + 32; k0 <= kend; k0 += 32) {
    bool more = (k0 < kend);
    if (more) LOADT(k0);
    COMPUTE(cur);
    if (more) {
      WRITET(cur ^ 1);
      BARRIER_NO_VMDRAIN();
      cur ^= 1;
    }
  }

  float* pz = part2 + (size_t)zb * R_ROIS * 128;
  #pragma unroll
  for (int m = 0; m < 4; ++m) {
    #pragma unroll
    for (int n = 0; n < 4; ++n) {
      int col = wn * 64 + n * 16 + lr;
      #pragma unroll
      for (int j = 0; j < 4; ++j) {
        int row = m0 + wm * 64 + m * 16 + kc * 4 + j;
        pz[(size_t)row * 128 + col] = acc[m][n][j];
      }
    }
  }
}

// --------- reduce head partials + bias, scatter to the two outputs ----------
__global__ __launch_bounds__(128) void reduce_head_kernel(
    const float* __restrict__ part2, const float* __restrict__ bc,
    const float* __restrict__ bs, float* __restrict__ out) {
  const int r = blockIdx.x, c = threadIdx.x;
  if (c >= NHEAD) return;
  float s = 0.0f;
  #pragma unroll
  for (int z = 0; z < ZSPLIT; ++z)
    s += part2[(size_t)z * R_ROIS * 128 + (size_t)r * 128 + c];
  if (c < 84)
    out[(size_t)r * 84 + c] = s + bc[c];
  else
    out[(size_t)R_ROIS * 84 + (size_t)r * 21 + (c - 84)] = s + bs[c - 84];
}

extern "C" void kernel_launch(void* const* d_in, const int* in_sizes, int n_in,
                              void* d_out, int out_size, void* d_ws, size_t ws_size,
                              hipStream_t stream) {
  const float* x    = (const float*)d_in[0];
  const float* rois = (const float*)d_in[1];
  const int*   ridx = (const int*)d_in[2];
  const float* W1   = (const float*)d_in[3];
  const float* b1   = (const float*)d_in[4];
  const float* W2   = (const float*)d_in[5];
  const float* b2   = (const float*)d_in[6];
  const float* Wc   = (const float*)d_in[7];
  const float* bc   = (const float*)d_in[8];
  const float* Wsv  = (const float*)d_in[9];
  const float* bs   = (const float*)d_in[10];

  const int MN = R_ROIS * NH;
  short* A     = (short*)d_ws;                    // [512][25088] bf16 (~25.7 MB)
  short* fc6   = A + (size_t)R_ROIS * KDIM;       // [512][4096]  bf16 (4 MB)
  short* fc7   = fc6 + (size_t)MN;                // [512][4096]  bf16 (4 MB)
  float* part  = (float*)(fc7 + (size_t)MN);      // 8 x [512][4096] f32 (67 MB)
  float* part2 = part + (size_t)ZSPLIT * MN;      // 8 x [512][128]  f32 (2 MB)
  short* Wt    = (short*)(part2 + (size_t)ZSPLIT * R_ROIS * 128);  // [128][4096] bf16

  roi_pool_kernel<<<dim3(R_ROIS, POOL_SLICES), 256, 0, stream>>>(x, rois, ridx, A);
  pack_head_w_kernel<<<128, 256, 0, stream>>>(Wc, Wsv, Wt);

  // fc6: [512,25088] @ [25088,4096]; 256 blocks (1/CU), Z=8
  gemm_splitk_kernel<<<256, 512, 0, stream>>>(A, W1, part, R_ROIS, NH, KDIM,
                                              KDIM / ZSPLIT, 256);
  reduce_relu_kernel<<<MN / 4 / 256, 256, 0, stream>>>(part, b1, fc6, MN, NH);

  // fc7: [512,4096] @ [4096,4096]; same 256^2 kernel, Z=8
  gemm_splitk_kernel<<<256, 512, 0, stream>>>(fc6, W2, part, R_ROIS, NH, NH,
                                              NH / ZSPLIT, 256);
  reduce_relu_kernel<<<MN / 4 / 256, 256, 0, stream>>>(part, b2, fc7, MN, NH);

  // heads: fc7 @ Wt^T via MFMA mini-GEMM (grid 4m x 8z), then bias+scatter
  gemm_head_kernel<<<dim3(4, ZSPLIT), 256, 0, stream>>>(fc7, Wt, part2);
  reduce_head_kernel<<<R_ROIS, 128, 0, stream>>>(part2, bc, bs, (float*)d_out);
}

// Round 18
// 273.037 us; speedup vs baseline: 1.2221x; 1.0634x over previous
//
#include <hip/hip_runtime.h>
#include <math.h>

typedef __attribute__((ext_vector_type(8))) short short8;
typedef __attribute__((ext_vector_type(4))) short s16x4;
typedef __attribute__((ext_vector_type(4))) float f32x4;
typedef __attribute__((ext_vector_type(4))) unsigned u32x4;

#define R_ROIS 512
#define CCH 512
#define HH 50
#define WW 50
#define PPOOL 7
#define KDIM (CCH * PPOOL * PPOOL) /* 25088 */
#define NH 4096
#define ZSPLIT 8
#define NHEAD 105 /* 84 cls + 21 scores */
#define POOL_SLICES 16

// raw barrier: lgkmcnt(0) publishes ds_writes; NO vmcnt drain -> prefetch
// loads stay in flight across the barrier (T4; __syncthreads would drain).
#define BARRIER_NO_VMDRAIN()                              \
  do {                                                    \
    asm volatile("s_waitcnt lgkmcnt(0)" ::: "memory");    \
    __builtin_amdgcn_s_barrier();                         \
  } while (0)

__device__ __forceinline__ short f2bf(float f) {
  unsigned u = __builtin_bit_cast(unsigned, f);
  u += 0x7FFFu + ((u >> 16) & 1u);
  return (short)(u >> 16);
}
__device__ __forceinline__ float bf2f(short s) {
  unsigned u = ((unsigned)(unsigned short)s) << 16;
  return __builtin_bit_cast(float, u);
}
// HW packed fp32->bf16 (RNE): 1 VALU per 2 elements
__device__ __forceinline__ unsigned cvtpk(float lo, float hi) {
  unsigned r;
  asm("v_cvt_pk_bf16_f32 %0, %1, %2" : "=v"(r) : "v"(lo), "v"(hi));
  return r;
}

// ---------------- RoI max pool -> bf16 activation matrix A[512][25088] ---------
// grid (R, 16): TLP for the latency-bound gather (~6 outputs/thread).
// Dynamic bounds nest (R15: static 3x3 was +10us). Thread-per-output layout
// (R11: channel-per-thread is 64x worse).
__global__ __launch_bounds__(256) void roi_pool_kernel(
    const float* __restrict__ x, const float* __restrict__ rois,
    const int* __restrict__ ridx, short* __restrict__ A) {
  __shared__ int hs[PPOOL], he[PPOOL], wss[PPOOL], wee[PPOOL];
  __shared__ int sidx;
  const int r = blockIdx.x;
  if (threadIdx.x == 0) {
    // raw rois columns: (ymin, xmin, ymax, xmax); reference permutes to (x,y,x,y)
    float ymin = rois[r * 4 + 0], xmin = rois[r * 4 + 1];
    float ymax = rois[r * 4 + 2], xmax = rois[r * 4 + 3];
    float sw = rintf(xmin * 0.0625f);
    float sh = rintf(ymin * 0.0625f);
    float ew = rintf(xmax * 0.0625f);
    float eh = rintf(ymax * 0.0625f);
    float bw = fmaxf(ew - sw + 1.0f, 1.0f) * (1.0f / 7.0f);
    float bh = fmaxf(eh - sh + 1.0f, 1.0f) * (1.0f / 7.0f);
    for (int p = 0; p < PPOOL; ++p) {
      wss[p] = (int)fminf(fmaxf(floorf(p * bw) + sw, 0.0f), 50.0f);
      wee[p] = (int)fminf(fmaxf(ceilf((p + 1) * bw) + sw, 0.0f), 50.0f);
      hs[p]  = (int)fminf(fmaxf(floorf(p * bh) + sh, 0.0f), 50.0f);
      he[p]  = (int)fminf(fmaxf(ceilf((p + 1) * bh) + sh, 0.0f), 50.0f);
    }
    sidx = ridx[r];
  }
  __syncthreads();
  const float* xb = x + (size_t)sidx * CCH * HH * WW;
  const int obeg = blockIdx.y * (KDIM / POOL_SLICES);
  const int oend = obeg + KDIM / POOL_SLICES;
  for (int o = obeg + threadIdx.x; o < oend; o += 256) {
    int c = o / 49;
    int pq = o - c * 49;
    int ph = pq / 7, pw = pq - ph * 7;
    const float* xc = xb + (size_t)c * (HH * WW);
    int h0 = hs[ph], h1 = he[ph], w0 = wss[pw], w1 = wee[pw];
    float mv = -INFINITY;
    for (int h = h0; h < h1; ++h) {
      const float* xr = xc + h * WW;
      for (int w = w0; w < w1; ++w) mv = fmaxf(mv, xr[w]);
    }
    A[(size_t)r * KDIM + o] = f2bf((h1 > h0 && w1 > w0) ? mv : 0.0f);
  }
}

// ---- bf16 MFMA split-K GEMM: BM=BN=256, BK=32, 512 thr, wave tile 128x64 ----
// grid = 2m x 16n x 8z = 256 blocks (1/CU). 2-deep register prefetch with TWO
// named reg sets + raw-barrier steps: tile i+2's loads stay in flight across
// the barrier (counted vmcnt at their ds_write). Chunked XCD swizzle: one
// z-slice per XCD. Partials stored BF16 (halves split-K traffic; rounding
// adds ~0.006 rms to fc6, diluted ~100x by downstream 0.01/0.001 weights).
__global__ __launch_bounds__(512, 2) void gemm_splitk_kernel(
    const short* __restrict__ A, const float* __restrict__ B,
    short* __restrict__ part, int M, int N, int K, int Ks, int nblk) {
  __shared__ __align__(16) char As[2][256 * 64];
  __shared__ __align__(16) char Bs[2][256 * 64];
  const int bid = blockIdx.x;
  const int vid = (bid & 7) * (nblk >> 3) + (bid >> 3);
  const int mb = vid & 1;
  const int nb = (vid >> 1) & 15;
  const int zb = vid >> 5;
  const int m0 = mb * 256, n0 = nb * 256;
  const int kbeg = zb * Ks;
  const int S = Ks >> 5;
  const int t = threadIdx.x;
  const int lane = t & 63, wid = t >> 6;  // 8 waves
  const int wm = wid >> 2, wn = wid & 3;  // 2m x 4n, wave tile 128x64
  const int lr = lane & 15, kc = lane >> 4;
  const int ar = t >> 1, ah = t & 1;      // A staging: row ar, 32B half ah
  const int bn = t & 255, bko = t >> 8;   // B staging: col bn, 16k-group bko

  const short* aptrA = A + (size_t)(m0 + ar) * K + ah * 16;
  const float* bbase = B + n0 + bn;

  const int awz0 = (ar * 64 + ah * 32) ^ ((ar & 7) << 4);
  const int awz1 = awz0 ^ 16;
  const int bwz0 = (bn * 64 + bko * 32) ^ ((bn & 7) << 4);
  const int bwz1 = bwz0 ^ 16;
  const int aoff = (wm * 8192 + lr * 64 + kc * 16) ^ ((lr & 7) << 4);
  const int boff = (wn * 4096 + lr * 64 + kc * 16) ^ ((lr & 7) << 4);

  f32x4 acc[8][4] = {};
  short8 aA0, aA1, aB0, aB1;
  float bA[16], bB[16];

  auto LOADT = [&](int k0, short8& r0, short8& r1, float* br) {
    r0 = *(const short8*)(aptrA + k0);
    r1 = *(const short8*)(aptrA + k0 + 8);
    const float* bp = bbase + (size_t)(k0 + bko * 16) * N;
    #pragma unroll
    for (int j = 0; j < 16; ++j) br[j] = bp[(size_t)j * N];
  };
  auto WRITET = [&](int buf, const short8& r0, const short8& r1, const float* br) {
    *(short8*)(As[buf] + awz0) = r0;
    *(short8*)(As[buf] + awz1) = r1;
    u32x4 w0, w1;
    w0[0] = cvtpk(br[0], br[1]);   w0[1] = cvtpk(br[2], br[3]);
    w0[2] = cvtpk(br[4], br[5]);   w0[3] = cvtpk(br[6], br[7]);
    w1[0] = cvtpk(br[8], br[9]);   w1[1] = cvtpk(br[10], br[11]);
    w1[2] = cvtpk(br[12], br[13]); w1[3] = cvtpk(br[14], br[15]);
    *(u32x4*)(Bs[buf] + bwz0) = w0;
    *(u32x4*)(Bs[buf] + bwz1) = w1;
  };
  auto COMPUTE = [&](int buf) {
    short8 b[4];
    #pragma unroll
    for (int n = 0; n < 4; ++n)
      b[n] = *(const short8*)(Bs[buf] + boff + n * 1024);
    #pragma unroll
    for (int m = 0; m < 8; ++m) {
      short8 a = *(const short8*)(As[buf] + aoff + m * 1024);
      #pragma unroll
      for (int n = 0; n < 4; ++n)
        acc[m][n] = __builtin_amdgcn_mfma_f32_16x16x32_bf16(a, b[n], acc[m][n], 0, 0, 0);
    }
  };

  LOADT(kbeg, aA0, aA1, bA);
  WRITET(0, aA0, aA1, bA);
  LOADT(kbeg + 32, aB0, aB1, bB);
  BARRIER_NO_VMDRAIN();

  int cur = 0;
  for (int i = 0; i < S; i += 2) {
    if (i + 2 < S) LOADT(kbeg + (i + 2) * 32, aA0, aA1, bA);
    COMPUTE(cur);
    WRITET(cur ^ 1, aB0, aB1, bB);
    BARRIER_NO_VMDRAIN();
    cur ^= 1;
    if (i + 3 < S) LOADT(kbeg + (i + 3) * 32, aB0, aB1, bB);
    COMPUTE(cur);
    if (i + 2 < S) {
      WRITET(cur ^ 1, aA0, aA1, bA);
      BARRIER_NO_VMDRAIN();
      cur ^= 1;
    }
  }

  // ---- write bf16 partial; C/D map: col=lane&15, row=kc*4+j ----
  short* pz = part + (size_t)zb * M * N;
  #pragma unroll
  for (int m = 0; m < 8; ++m) {
    #pragma unroll
    for (int n = 0; n < 4; ++n) {
      int col = n0 + wn * 64 + n * 16 + lr;
      #pragma unroll
      for (int j = 0; j < 4; ++j) {
        int row = m0 + wm * 128 + m * 16 + kc * 4 + j;
        pz[(size_t)row * N + col] = f2bf(acc[m][n][j]);
      }
    }
  }
}

// ----------- reduce bf16 split-K partials + bias + relu -> bf16 ---------------
__global__ __launch_bounds__(256) void reduce_relu_kernel(
    const short* __restrict__ part, const float* __restrict__ bias,
    short* __restrict__ out, int MN, int N) {
  int i = (blockIdx.x * 256 + threadIdx.x) * 4;
  if (i >= MN) return;
  const float4 b = *(const float4*)(bias + (i & (N - 1)));
  float s0 = 0.0f, s1 = 0.0f, s2 = 0.0f, s3 = 0.0f;
  #pragma unroll
  for (int z = 0; z < ZSPLIT; ++z) {
    s16x4 p = *(const s16x4*)(part + (size_t)z * MN + i);
    s0 += bf2f(p.x); s1 += bf2f(p.y); s2 += bf2f(p.z); s3 += bf2f(p.w);
  }
  s16x4 o;
  o.x = f2bf(fmaxf(s0 + b.x, 0.0f));
  o.y = f2bf(fmaxf(s1 + b.y, 0.0f));
  o.z = f2bf(fmaxf(s2 + b.z, 0.0f));
  o.w = f2bf(fmaxf(s3 + b.w, 0.0f));
  *(s16x4*)(out + i) = o;
}

// ------------- pack Wc[4096,84] | Ws[4096,21] -> Wt bf16 [128][4096] ----------
__global__ __launch_bounds__(256) void pack_head_w_kernel(
    const float* __restrict__ Wc, const float* __restrict__ Wsv,
    short* __restrict__ Wt) {
  const int n = blockIdx.x;  // 0..127
  for (int k = threadIdx.x; k < NH; k += 256) {
    float v = 0.0f;
    if (n < 84) v = Wc[(size_t)k * 84 + n];
    else if (n < NHEAD) v = Wsv[(size_t)k * 21 + (n - 84)];
    Wt[(size_t)n * NH + k] = f2bf(v);
  }
}

// ---- head mini-GEMM: fc7[512,4096]bf16 @ Wt[128,4096]bf16 -> part2 fp32 -----
// BM=BN=128, BK=32, 256 thr (4 waves 2x2, wave tile 64x64), grid (4m, 8z).
__global__ __launch_bounds__(256, 2) void gemm_head_kernel(
    const short* __restrict__ A, const short* __restrict__ Bt,
    float* __restrict__ part2) {
  __shared__ __align__(16) char As[2][128 * 64];
  __shared__ __align__(16) char Bs[2][128 * 64];
  const int m0 = blockIdx.x * 128;
  const int zb = blockIdx.y;
  const int kbeg = zb * (NH / ZSPLIT), kend = kbeg + NH / ZSPLIT;
  const int t = threadIdx.x;
  const int lane = t & 63, wid = t >> 6;
  const int wm = wid >> 1, wn = wid & 1;
  const int lr = lane & 15, kc = lane >> 4;
  const int sr = t >> 2, seg = t & 3;

  const short* aptr0 = A + (size_t)(m0 + sr) * NH + seg * 8;
  const short* aptr1 = aptr0 + (size_t)64 * NH;
  const short* bptr0 = Bt + (size_t)sr * NH + seg * 8;
  const short* bptr1 = bptr0 + (size_t)64 * NH;

  const int wz0 = (sr * 64 + seg * 16) ^ ((sr & 7) << 4);
  const int wz1 = wz0 + 4096;
  const int aoff = (wm * 4096 + lr * 64 + kc * 16) ^ ((lr & 7) << 4);
  const int boff = (wn * 4096 + lr * 64 + kc * 16) ^ ((lr & 7) << 4);

  f32x4 acc[4][4] = {};
  short8 a_r0, a_r1, b_r0, b_r1;

  auto LOADT = [&](int k0) {
    a_r0 = *(const short8*)(aptr0 + k0);
    a_r1 = *(const short8*)(aptr1 + k0);
    b_r0 = *(const short8*)(bptr0 + k0);
    b_r1 = *(const short8*)(bptr1 + k0);
  };
  auto WRITET = [&](int buf) {
    *(short8*)(As[buf] + wz0) = a_r0;
    *(short8*)(As[buf] + wz1) = a_r1;
    *(short8*)(Bs[buf] + wz0) = b_r0;
    *(short8*)(Bs[buf] + wz1) = b_r1;
  };
  auto COMPUTE = [&](int buf) {
    short8 a[4], b[4];
    #pragma unroll
    for (int m = 0; m < 4; ++m)
      a[m] = *(const short8*)(As[buf] + aoff + m * 1024);
    #pragma unroll
    for (int n = 0; n < 4; ++n)
      b[n] = *(const short8*)(Bs[buf] + boff + n * 1024);
    #pragma unroll
    for (int m = 0; m < 4; ++m)
      #pragma unroll
      for (int n = 0; n < 4; ++n)
        acc[m][n] = __builtin_amdgcn_mfma_f32_16x16x32_bf16(a[m], b[n], acc[m][n], 0, 0, 0);
  };

  LOADT(kbeg);
  WRITET(0);
  BARRIER_NO_VMDRAIN();

  int cur = 0;
  for (int k0 = kbeg + 32; k0 <= kend; k0 += 32) {
    bool more = (k0 < kend);
    if (more) LOADT(k0);
    COMPUTE(cur);
    if (more) {
      WRITET(cur ^ 1);
      BARRIER_NO_VMDRAIN();
      cur ^= 1;
    }
  }

  float* pz = part2 + (size_t)zb * R_ROIS * 128;
  #pragma unroll
  for (int m = 0; m < 4; ++m) {
    #pragma unroll
    for (int n = 0; n < 4; ++n) {
      int col = wn * 64 + n * 16 + lr;
      #pragma unroll
      for (int j = 0; j < 4; ++j) {
        int row = m0 + wm * 64 + m * 16 + kc * 4 + j;
        pz[(size_t)row * 128 + col] = acc[m][n][j];
      }
    }
  }
}

// --------- reduce head partials + bias, scatter to the two outputs ----------
__global__ __launch_bounds__(128) void reduce_head_kernel(
    const float* __restrict__ part2, const float* __restrict__ bc,
    const float* __restrict__ bs, float* __restrict__ out) {
  const int r = blockIdx.x, c = threadIdx.x;
  if (c >= NHEAD) return;
  float s = 0.0f;
  #pragma unroll
  for (int z = 0; z < ZSPLIT; ++z)
    s += part2[(size_t)z * R_ROIS * 128 + (size_t)r * 128 + c];
  if (c < 84)
    out[(size_t)r * 84 + c] = s + bc[c];
  else
    out[(size_t)R_ROIS * 84 + (size_t)r * 21 + (c - 84)] = s + bs[c - 84];
}

extern "C" void kernel_launch(void* const* d_in, const int* in_sizes, int n_in,
                              void* d_out, int out_size, void* d_ws, size_t ws_size,
                              hipStream_t stream) {
  const float* x    = (const float*)d_in[0];
  const float* rois = (const float*)d_in[1];
  const int*   ridx = (const int*)d_in[2];
  const float* W1   = (const float*)d_in[3];
  const float* b1   = (const float*)d_in[4];
  const float* W2   = (const float*)d_in[5];
  const float* b2   = (const float*)d_in[6];
  const float* Wc   = (const float*)d_in[7];
  const float* bc   = (const float*)d_in[8];
  const float* Wsv  = (const float*)d_in[9];
  const float* bs   = (const float*)d_in[10];

  const int MN = R_ROIS * NH;
  short* A     = (short*)d_ws;                    // [512][25088] bf16 (~25.7 MB)
  short* fc6   = A + (size_t)R_ROIS * KDIM;       // [512][4096]  bf16 (4 MB)
  short* fc7   = fc6 + (size_t)MN;                // [512][4096]  bf16 (4 MB)
  short* part  = fc7 + (size_t)MN;                // 8 x [512][4096] bf16 (33.5 MB)
  float* part2 = (float*)(part + (size_t)ZSPLIT * MN);  // 8 x [512][128] f32 (2 MB)
  short* Wt    = (short*)(part2 + (size_t)ZSPLIT * R_ROIS * 128);  // [128][4096] bf16

  roi_pool_kernel<<<dim3(R_ROIS, POOL_SLICES), 256, 0, stream>>>(x, rois, ridx, A);
  pack_head_w_kernel<<<128, 256, 0, stream>>>(Wc, Wsv, Wt);

  // fc6: [512,25088] @ [25088,4096]; 256 blocks (1/CU), Z=8
  gemm_splitk_kernel<<<256, 512, 0, stream>>>(A, W1, part, R_ROIS, NH, KDIM,
                                              KDIM / ZSPLIT, 256);
  reduce_relu_kernel<<<MN / 4 / 256, 256, 0, stream>>>(part, b1, fc6, MN, NH);

  // fc7: [512,4096] @ [4096,4096]; same 256^2 kernel, Z=8
  gemm_splitk_kernel<<<256, 512, 0, stream>>>(fc6, W2, part, R_ROIS, NH, NH,
                                              NH / ZSPLIT, 256);
  reduce_relu_kernel<<<MN / 4 / 256, 256, 0, stream>>>(part, b2, fc7, MN, NH);

  // heads: fc7 @ Wt^T via MFMA mini-GEMM (grid 4m x 8z), then bias+scatter
  gemm_head_kernel<<<dim3(4, ZSPLIT), 256, 0, stream>>>(fc7, Wt, part2);
  reduce_head_kernel<<<R_ROIS, 128, 0, stream>>>(part2, bc, bs, (float*)d_out);
}

// Round 19
// 270.069 us; speedup vs baseline: 1.2356x; 1.0110x over previous
//
#include <hip/hip_runtime.h>
#include <math.h>

typedef __attribute__((ext_vector_type(8))) short short8;
typedef __attribute__((ext_vector_type(4))) short s16x4;
typedef __attribute__((ext_vector_type(4))) float f32x4;
typedef __attribute__((ext_vector_type(4))) unsigned u32x4;

#define R_ROIS 512
#define CCH 512
#define HH 50
#define WW 50
#define PPOOL 7
#define KDIM (CCH * PPOOL * PPOOL) /* 25088 */
#define NH 4096
#define ZSPLIT 8
#define NHEAD 105 /* 84 cls + 21 scores */
#define POOL_SLICES 16

// raw barrier: lgkmcnt(0) publishes ds_writes; NO vmcnt drain -> prefetch
// loads stay in flight across the barrier (T4; __syncthreads would drain).
#define BARRIER_NO_VMDRAIN()                              \
  do {                                                    \
    asm volatile("s_waitcnt lgkmcnt(0)" ::: "memory");    \
    __builtin_amdgcn_s_barrier();                         \
  } while (0)

__device__ __forceinline__ short f2bf(float f) {
  unsigned u = __builtin_bit_cast(unsigned, f);
  u += 0x7FFFu + ((u >> 16) & 1u);
  return (short)(u >> 16);
}
__device__ __forceinline__ float bf2f(short s) {
  unsigned u = ((unsigned)(unsigned short)s) << 16;
  return __builtin_bit_cast(float, u);
}
// HW packed fp32->bf16 (RNE): 1 VALU per 2 elements
__device__ __forceinline__ unsigned cvtpk(float lo, float hi) {
  unsigned r;
  asm("v_cvt_pk_bf16_f32 %0, %1, %2" : "=v"(r) : "v"(lo), "v"(hi));
  return r;
}

// ---------------- RoI max pool -> bf16 activation matrix A[512][25088] ---------
// grid (R, 16): TLP for the latency-bound gather. Dynamic bounds nest (R15:
// static 3x3 was +10us). Thread-per-output (R11: channel-per-thread 64x worse).
__global__ __launch_bounds__(256) void roi_pool_kernel(
    const float* __restrict__ x, const float* __restrict__ rois,
    const int* __restrict__ ridx, short* __restrict__ A) {
  __shared__ int hs[PPOOL], he[PPOOL], wss[PPOOL], wee[PPOOL];
  __shared__ int sidx;
  const int r = blockIdx.x;
  if (threadIdx.x == 0) {
    // raw rois columns: (ymin, xmin, ymax, xmax); reference permutes to (x,y,x,y)
    float ymin = rois[r * 4 + 0], xmin = rois[r * 4 + 1];
    float ymax = rois[r * 4 + 2], xmax = rois[r * 4 + 3];
    float sw = rintf(xmin * 0.0625f);
    float sh = rintf(ymin * 0.0625f);
    float ew = rintf(xmax * 0.0625f);
    float eh = rintf(ymax * 0.0625f);
    float bw = fmaxf(ew - sw + 1.0f, 1.0f) * (1.0f / 7.0f);
    float bh = fmaxf(eh - sh + 1.0f, 1.0f) * (1.0f / 7.0f);
    for (int p = 0; p < PPOOL; ++p) {
      wss[p] = (int)fminf(fmaxf(floorf(p * bw) + sw, 0.0f), 50.0f);
      wee[p] = (int)fminf(fmaxf(ceilf((p + 1) * bw) + sw, 0.0f), 50.0f);
      hs[p]  = (int)fminf(fmaxf(floorf(p * bh) + sh, 0.0f), 50.0f);
      he[p]  = (int)fminf(fmaxf(ceilf((p + 1) * bh) + sh, 0.0f), 50.0f);
    }
    sidx = ridx[r];
  }
  __syncthreads();
  const float* xb = x + (size_t)sidx * CCH * HH * WW;
  const int obeg = blockIdx.y * (KDIM / POOL_SLICES);
  const int oend = obeg + KDIM / POOL_SLICES;
  for (int o = obeg + threadIdx.x; o < oend; o += 256) {
    int c = o / 49;
    int pq = o - c * 49;
    int ph = pq / 7, pw = pq - ph * 7;
    const float* xc = xb + (size_t)c * (HH * WW);
    int h0 = hs[ph], h1 = he[ph], w0 = wss[pw], w1 = wee[pw];
    float mv = -INFINITY;
    for (int h = h0; h < h1; ++h) {
      const float* xr = xc + h * WW;
      for (int w = w0; w < w1; ++w) mv = fmaxf(mv, xr[w]);
    }
    A[(size_t)r * KDIM + o] = f2bf((h1 > h0 && w1 > w0) ? mv : 0.0f);
  }
}

// ---- bf16 MFMA split-K GEMM: BM=BN=256, BK=64, 512 thr, wave tile 128x64 ----
// grid = 2m x 16n x 8z = 256 blocks (1/CU). BK=64 halves barrier events per
// FLOP (49 steps vs 98); step ~2400cy >> 900cy HBM latency so 1-deep prefetch
// suffices. LDS 128KB/block: fine at 1 block/CU (no occupancy change - m132's
// BK-unroll regression was an occupancy cut, N/A here). Rows are 128B; swizzle
// slot=(k/8)^(row&7), kk-subtile = byte^64. Raw lgkm-only barriers (R13).
// Partials bf16 (R18). Chunked XCD swizzle: one z-slice per XCD.
__global__ __launch_bounds__(512, 2) void gemm_splitk_kernel(
    const short* __restrict__ A, const float* __restrict__ B,
    short* __restrict__ part, int M, int N, int K, int Ks, int nblk) {
  __shared__ __align__(16) char As[2][256 * 128];
  __shared__ __align__(16) char Bs[2][256 * 128];
  const int bid = blockIdx.x;
  const int vid = (bid & 7) * (nblk >> 3) + (bid >> 3);
  const int mb = vid & 1;
  const int nb = (vid >> 1) & 15;
  const int zb = vid >> 5;
  const int m0 = mb * 256, n0 = nb * 256;
  const int kbeg = zb * Ks, kend = kbeg + Ks;
  const int t = threadIdx.x;
  const int lane = t & 63, wid = t >> 6;  // 8 waves
  const int wm = wid >> 2, wn = wid & 3;  // 2m x 4n, wave tile 128x64
  const int lr = lane & 15, kc = lane >> 4;
  const int ar = t >> 1, ah = t & 1;      // A staging: row ar, 64B k-half ah
  const int bn = t & 255, bko = t >> 8;   // B staging: col bn, 32k-half bko

  const short* aptrA = A + (size_t)(m0 + ar) * K + ah * 32;
  const float* bbase = B + n0 + bn;

  // swizzled staging byte offsets: slot j in [0,8) of a 128B row, ^ (row&7)
  int awz[4], bwz[4];
  #pragma unroll
  for (int j = 0; j < 4; ++j) {
    awz[j] = ar * 128 + (((ah * 4 + j) ^ (ar & 7)) << 4);
    bwz[j] = bn * 128 + (((bko * 4 + j) ^ (bn & 7)) << 4);
  }
  // fragment read bases (kk=1 subtile at base^64; +m*2048 / +n*2048 rows)
  const int aoff = (wm * 128 + lr) * 128 + ((kc ^ (lr & 7)) << 4);
  const int boff = (wn * 64 + lr) * 128 + ((kc ^ (lr & 7)) << 4);

  f32x4 acc[8][4] = {};
  short8 a_r0, a_r1, a_r2, a_r3;
  float br[32];

  auto LOADT = [&](int k0) {
    a_r0 = *(const short8*)(aptrA + k0);
    a_r1 = *(const short8*)(aptrA + k0 + 8);
    a_r2 = *(const short8*)(aptrA + k0 + 16);
    a_r3 = *(const short8*)(aptrA + k0 + 24);
    const float* bp = bbase + (size_t)(k0 + bko * 32) * N;
    #pragma unroll
    for (int j = 0; j < 32; ++j) br[j] = bp[(size_t)j * N];
  };
  auto WRITET = [&](int buf) {
    *(short8*)(As[buf] + awz[0]) = a_r0;
    *(short8*)(As[buf] + awz[1]) = a_r1;
    *(short8*)(As[buf] + awz[2]) = a_r2;
    *(short8*)(As[buf] + awz[3]) = a_r3;
    #pragma unroll
    for (int j = 0; j < 4; ++j) {
      u32x4 w;
      w[0] = cvtpk(br[j * 8 + 0], br[j * 8 + 1]);
      w[1] = cvtpk(br[j * 8 + 2], br[j * 8 + 3]);
      w[2] = cvtpk(br[j * 8 + 4], br[j * 8 + 5]);
      w[3] = cvtpk(br[j * 8 + 6], br[j * 8 + 7]);
      *(u32x4*)(Bs[buf] + bwz[j]) = w;
    }
  };
  auto COMPUTE = [&](int buf) {
    #pragma unroll
    for (int kk = 0; kk < 2; ++kk) {
      short8 b[4];
      #pragma unroll
      for (int n = 0; n < 4; ++n)
        b[n] = *(const short8*)(Bs[buf] + ((boff + n * 2048) ^ (kk << 6)));
      #pragma unroll
      for (int m = 0; m < 8; ++m) {
        short8 a = *(const short8*)(As[buf] + ((aoff + m * 2048) ^ (kk << 6)));
        #pragma unroll
        for (int n = 0; n < 4; ++n)
          acc[m][n] = __builtin_amdgcn_mfma_f32_16x16x32_bf16(a, b[n], acc[m][n], 0, 0, 0);
      }
    }
  };

  LOADT(kbeg);
  WRITET(0);
  BARRIER_NO_VMDRAIN();

  int cur = 0;
  for (int k0 = kbeg + 64; k0 <= kend; k0 += 64) {
    bool more = (k0 < kend);
    if (more) LOADT(k0);   // loads stay in flight past the raw barrier
    COMPUTE(cur);
    if (more) {
      WRITET(cur ^ 1);     // counted vmcnt wait on this tile's loads only
      BARRIER_NO_VMDRAIN();
      cur ^= 1;
    }
  }

  // ---- write bf16 partial; C/D map: col=lane&15, row=kc*4+j ----
  short* pz = part + (size_t)zb * M * N;
  #pragma unroll
  for (int m = 0; m < 8; ++m) {
    #pragma unroll
    for (int n = 0; n < 4; ++n) {
      int col = n0 + wn * 64 + n * 16 + lr;
      #pragma unroll
      for (int j = 0; j < 4; ++j) {
        int row = m0 + wm * 128 + m * 16 + kc * 4 + j;
        pz[(size_t)row * N + col] = f2bf(acc[m][n][j]);
      }
    }
  }
}

// ----------- reduce bf16 split-K partials + bias + relu -> bf16 ---------------
__global__ __launch_bounds__(256) void reduce_relu_kernel(
    const short* __restrict__ part, const float* __restrict__ bias,
    short* __restrict__ out, int MN, int N) {
  int i = (blockIdx.x * 256 + threadIdx.x) * 4;
  if (i >= MN) return;
  const float4 b = *(const float4*)(bias + (i & (N - 1)));
  float s0 = 0.0f, s1 = 0.0f, s2 = 0.0f, s3 = 0.0f;
  #pragma unroll
  for (int z = 0; z < ZSPLIT; ++z) {
    s16x4 p = *(const s16x4*)(part + (size_t)z * MN + i);
    s0 += bf2f(p.x); s1 += bf2f(p.y); s2 += bf2f(p.z); s3 += bf2f(p.w);
  }
  s16x4 o;
  o.x = f2bf(fmaxf(s0 + b.x, 0.0f));
  o.y = f2bf(fmaxf(s1 + b.y, 0.0f));
  o.z = f2bf(fmaxf(s2 + b.z, 0.0f));
  o.w = f2bf(fmaxf(s3 + b.w, 0.0f));
  *(s16x4*)(out + i) = o;
}

// ------------- pack Wc[4096,84] | Ws[4096,21] -> Wt bf16 [128][4096] ----------
__global__ __launch_bounds__(256) void pack_head_w_kernel(
    const float* __restrict__ Wc, const float* __restrict__ Wsv,
    short* __restrict__ Wt) {
  const int n = blockIdx.x;  // 0..127
  for (int k = threadIdx.x; k < NH; k += 256) {
    float v = 0.0f;
    if (n < 84) v = Wc[(size_t)k * 84 + n];
    else if (n < NHEAD) v = Wsv[(size_t)k * 21 + (n - 84)];
    Wt[(size_t)n * NH + k] = f2bf(v);
  }
}

// ---- head mini-GEMM: fc7[512,4096]bf16 @ Wt[128,4096]bf16 -> part2 fp32 -----
// BM=BN=128, BK=32, 256 thr (4 waves 2x2, wave tile 64x64), grid (4m, 8z).
__global__ __launch_bounds__(256, 2) void gemm_head_kernel(
    const short* __restrict__ A, const short* __restrict__ Bt,
    float* __restrict__ part2) {
  __shared__ __align__(16) char As[2][128 * 64];
  __shared__ __align__(16) char Bs[2][128 * 64];
  const int m0 = blockIdx.x * 128;
  const int zb = blockIdx.y;
  const int kbeg = zb * (NH / ZSPLIT), kend = kbeg + NH / ZSPLIT;
  const int t = threadIdx.x;
  const int lane = t & 63, wid = t >> 6;
  const int wm = wid >> 1, wn = wid & 1;
  const int lr = lane & 15, kc = lane >> 4;
  const int sr = t >> 2, seg = t & 3;

  const short* aptr0 = A + (size_t)(m0 + sr) * NH + seg * 8;
  const short* aptr1 = aptr0 + (size_t)64 * NH;
  const short* bptr0 = Bt + (size_t)sr * NH + seg * 8;
  const short* bptr1 = bptr0 + (size_t)64 * NH;

  const int wz0 = (sr * 64 + seg * 16) ^ ((sr & 7) << 4);
  const int wz1 = wz0 + 4096;
  const int aoff = (wm * 4096 + lr * 64 + kc * 16) ^ ((lr & 7) << 4);
  const int boff = (wn * 4096 + lr * 64 + kc * 16) ^ ((lr & 7) << 4);

  f32x4 acc[4][4] = {};
  short8 a_r0, a_r1, b_r0, b_r1;

  auto LOADT = [&](int k0) {
    a_r0 = *(const short8*)(aptr0 + k0);
    a_r1 = *(const short8*)(aptr1 + k0);
    b_r0 = *(const short8*)(bptr0 + k0);
    b_r1 = *(const short8*)(bptr1 + k0);
  };
  auto WRITET = [&](int buf) {
    *(short8*)(As[buf] + wz0) = a_r0;
    *(short8*)(As[buf] + wz1) = a_r1;
    *(short8*)(Bs[buf] + wz0) = b_r0;
    *(short8*)(Bs[buf] + wz1) = b_r1;
  };
  auto COMPUTE = [&](int buf) {
    short8 a[4], b[4];
    #pragma unroll
    for (int m = 0; m < 4; ++m)
      a[m] = *(const short8*)(As[buf] + aoff + m * 1024);
    #pragma unroll
    for (int n = 0; n < 4; ++n)
      b[n] = *(const short8*)(Bs[buf] + boff + n * 1024);
    #pragma unroll
    for (int m = 0; m < 4; ++m)
      #pragma unroll
      for (int n = 0; n < 4; ++n)
        acc[m][n] = __builtin_amdgcn_mfma_f32_16x16x32_bf16(a[m], b[n], acc[m][n], 0, 0, 0);
  };

  LOADT(kbeg);
  WRITET(0);
  BARRIER_NO_VMDRAIN();

  int cur = 0;
  for (int k0 = kbeg + 32; k0 <= kend; k0 += 32) {
    bool more = (k0 < kend);
    if (more) LOADT(k0);
    COMPUTE(cur);
    if (more) {
      WRITET(cur ^ 1);
      BARRIER_NO_VMDRAIN();
      cur ^= 1;
    }
  }

  float* pz = part2 + (size_t)zb * R_ROIS * 128;
  #pragma unroll
  for (int m = 0; m < 4; ++m) {
    #pragma unroll
    for (int n = 0; n < 4; ++n) {
      int col = wn * 64 + n * 16 + lr;
      #pragma unroll
      for (int j = 0; j < 4; ++j) {
        int row = m0 + wm * 64 + m * 16 + kc * 4 + j;
        pz[(size_t)row * 128 + col] = acc[m][n][j];
      }
    }
  }
}

// --------- reduce head partials + bias, scatter to the two outputs ----------
__global__ __launch_bounds__(128) void reduce_head_kernel(
    const float* __restrict__ part2, const float* __restrict__ bc,
    const float* __restrict__ bs, float* __restrict__ out) {
  const int r = blockIdx.x, c = threadIdx.x;
  if (c >= NHEAD) return;
  float s = 0.0f;
  #pragma unroll
  for (int z = 0; z < ZSPLIT; ++z)
    s += part2[(size_t)z * R_ROIS * 128 + (size_t)r * 128 + c];
  if (c < 84)
    out[(size_t)r * 84 + c] = s + bc[c];
  else
    out[(size_t)R_ROIS * 84 + (size_t)r * 21 + (c - 84)] = s + bs[c - 84];
}

extern "C" void kernel_launch(void* const* d_in, const int* in_sizes, int n_in,
                              void* d_out, int out_size, void* d_ws, size_t ws_size,
                              hipStream_t stream) {
  const float* x    = (const float*)d_in[0];
  const float* rois = (const float*)d_in[1];
  const int*   ridx = (const int*)d_in[2];
  const float* W1   = (const float*)d_in[3];
  const float* b1   = (const float*)d_in[4];
  const float* W2   = (const float*)d_in[5];
  const float* b2   = (const float*)d_in[6];
  const float* Wc   = (const float*)d_in[7];
  const float* bc   = (const float*)d_in[8];
  const float* Wsv  = (const float*)d_in[9];
  const float* bs   = (const float*)d_in[10];

  const int MN = R_ROIS * NH;
  short* A     = (short*)d_ws;                    // [512][25088] bf16 (~25.7 MB)
  short* fc6   = A + (size_t)R_ROIS * KDIM;       // [512][4096]  bf16 (4 MB)
  short* fc7   = fc6 + (size_t)MN;                // [512][4096]  bf16 (4 MB)
  short* part  = fc7 + (size_t)MN;                // 8 x [512][4096] bf16 (33.5 MB)
  float* part2 = (float*)(part + (size_t)ZSPLIT * MN);  // 8 x [512][128] f32 (2 MB)
  short* Wt    = (short*)(part2 + (size_t)ZSPLIT * R_ROIS * 128);  // [128][4096] bf16

  roi_pool_kernel<<<dim3(R_ROIS, POOL_SLICES), 256, 0, stream>>>(x, rois, ridx, A);
  pack_head_w_kernel<<<128, 256, 0, stream>>>(Wc, Wsv, Wt);

  // fc6: [512,25088] @ [25088,4096]; 256 blocks (1/CU), Z=8, BK=64
  gemm_splitk_kernel<<<256, 512, 0, stream>>>(A, W1, part, R_ROIS, NH, KDIM,
                                              KDIM / ZSPLIT, 256);
  reduce_relu_kernel<<<MN / 4 / 256, 256, 0, stream>>>(part, b1, fc6, MN, NH);

  // fc7: [512,4096] @ [4096,4096]; same kernel, Z=8, BK=64
  gemm_splitk_kernel<<<256, 512, 0, stream>>>(fc6, W2, part, R_ROIS, NH, NH,
                                              NH / ZSPLIT, 256);
  reduce_relu_kernel<<<MN / 4 / 256, 256, 0, stream>>>(part, b2, fc7, MN, NH);

  // heads: fc7 @ Wt^T via MFMA mini-GEMM (grid 4m x 8z), then bias+scatter
  gemm_head_kernel<<<dim3(4, ZSPLIT), 256, 0, stream>>>(fc7, Wt, part2);
  reduce_head_kernel<<<R_ROIS, 128, 0, stream>>>(part2, bc, bs, (float*)d_out);
}